// Round 8
// baseline (374.089 us; speedup 1.0000x reference)
//
#include <hip/hip_runtime.h>
#include <math.h>

#define N_NODES 50000
#define N_EDGES 800000
#define NB 32
#define NA 128
#define CJ_BLOCKS 782           // (N_NODES+63)/64
#define CNT_BLOCKS 3125         // N_EDGES/256 exactly
#define EDGE_BLOCKS 3125        // N_EDGES/256 exactly
#define SCAN_BLOCKS 49          // ceil(N_NODES/1024)
#define AGG_BLOCKS 782          // 64 nodes/block

constexpr double STEP_D = 10.0 / 31.0;
constexpr float  STEP_F = (float)(10.0 / 31.0);       // matches np.float32 width
constexpr float  COEFF  = -0.5f / (STEP_F * STEP_F);  // -0.5/width^2
constexpr float  R2     = 1.41421356237309515f;       // sqrt(2) = PREF2 for mixed terms
constexpr float  INV_STEP = 3.1f;                     // 31/10
constexpr float  HWIN   = 2.05f;                      // g(HWIN) ~ 1.7e-9

__device__ __forceinline__ float fast_rcp(float x) {
    return __builtin_amdgcn_rcpf(x);   // v_rcp_f32, ~1ulp
}

__device__ __forceinline__ float silu_f(float x) {
    return x * fast_rcp(1.0f + __expf(-x));
}

// ---------------- A: fused cj-MLP (blocks < CJ_BLOCKS) + edge count (rest) --------
__global__ __launch_bounds__(256) void k_cj_count(const float* __restrict__ feat,
                                                  const float* __restrict__ w1,
                                                  const float* __restrict__ b1,
                                                  const float* __restrict__ w2,
                                                  const float* __restrict__ b2,
                                                  float* __restrict__ cj,
                                                  const int* __restrict__ src,
                                                  int* __restrict__ cnt) {
    __shared__ float fls[64 * 128];   // 32 KB feat tile (unused by count blocks)
    int tid = threadIdx.x;
    int blk = blockIdx.x;
    if (blk >= CJ_BLOCKS) {
        int e = (blk - CJ_BLOCKS) * 256 + tid;
        if (e < N_EDGES) atomicAdd(&cnt[src[e]], 1);
        return;
    }
    int jq  = tid & 31;          // j quad: j0 = 4*jq
    int ng  = tid >> 5;          // node group 0..7 (8 nodes each)
    int j0  = jq * 4;
    int n0  = blk * 64;

    // stage feat tile (coalesced float4, clamped for tail block)
    {
        const float4* fp = (const float4*)feat;
        int base = n0 * 32;                    // float4 index
        int maxi = N_NODES * 32 - 1;
#pragma unroll
        for (int r = 0; r < 8; r++) {
            int idx = base + r * 256 + tid;
            ((float4*)fls)[r * 256 + tid] = fp[min(idx, maxi)];
        }
    }
    __syncthreads();

    float4 bv = *(const float4*)&b1[j0];
    float h[8][4];
#pragma unroll
    for (int i = 0; i < 8; i++) {
        h[i][0] = bv.x; h[i][1] = bv.y; h[i][2] = bv.z; h[i][3] = bv.w;
    }
    for (int kb = 0; kb < 128; kb += 4) {
        float4 wv[4];
#pragma unroll
        for (int u = 0; u < 4; u++) wv[u] = *(const float4*)&w1[(kb + u) * 128 + j0];
#pragma unroll
        for (int i = 0; i < 8; i++) {
            float4 f4 = *(const float4*)&fls[(ng * 8 + i) * 128 + kb];
            h[i][0] = fmaf(f4.x, wv[0].x, h[i][0]);
            h[i][1] = fmaf(f4.x, wv[0].y, h[i][1]);
            h[i][2] = fmaf(f4.x, wv[0].z, h[i][2]);
            h[i][3] = fmaf(f4.x, wv[0].w, h[i][3]);
            h[i][0] = fmaf(f4.y, wv[1].x, h[i][0]);
            h[i][1] = fmaf(f4.y, wv[1].y, h[i][1]);
            h[i][2] = fmaf(f4.y, wv[1].z, h[i][2]);
            h[i][3] = fmaf(f4.y, wv[1].w, h[i][3]);
            h[i][0] = fmaf(f4.z, wv[2].x, h[i][0]);
            h[i][1] = fmaf(f4.z, wv[2].y, h[i][1]);
            h[i][2] = fmaf(f4.z, wv[2].z, h[i][2]);
            h[i][3] = fmaf(f4.z, wv[2].w, h[i][3]);
            h[i][0] = fmaf(f4.w, wv[3].x, h[i][0]);
            h[i][1] = fmaf(f4.w, wv[3].y, h[i][1]);
            h[i][2] = fmaf(f4.w, wv[3].z, h[i][2]);
            h[i][3] = fmaf(f4.w, wv[3].w, h[i][3]);
        }
    }
    // epilogue: cj[n] = b2 + sum_j silu(h)*w2[j]; reduce across the 32-lane jq group
    float4 w2v = *(const float4*)&w2[j0];
    float keep = 0.f;
#pragma unroll
    for (int i = 0; i < 8; i++) {
        float v = silu_f(h[i][0]) * w2v.x + silu_f(h[i][1]) * w2v.y
                + silu_f(h[i][2]) * w2v.z + silu_f(h[i][3]) * w2v.w;
#pragma unroll
        for (int m = 1; m < 32; m <<= 1) v += __shfl_xor(v, m, 64);
        if (jq == i) keep = v;
    }
    if (jq < 8) {
        int n = n0 + ng * 8 + jq;
        if (n < N_NODES) cj[n] = b2[0] + keep;
    }
}

// ---------------- B: single-kernel scan (49 co-resident blocks, flag sync) -------
__global__ __launch_bounds__(1024) void k_scan(const int* __restrict__ cnt,
                                               int* __restrict__ offs,
                                               int* __restrict__ cursor,
                                               int* __restrict__ bsum) {
    __shared__ int s[1024];
    __shared__ int sbase;
    int bid = blockIdx.x;
    int i = bid * 1024 + threadIdx.x;
    int v = (i < N_NODES) ? cnt[i] : 0;
    s[threadIdx.x] = v;
    __syncthreads();
    for (int o = 1; o < 1024; o <<= 1) {
        int t = (threadIdx.x >= (unsigned)o) ? s[threadIdx.x - o] : 0;
        __syncthreads();
        s[threadIdx.x] += t;
        __syncthreads();
    }
    if (threadIdx.x == 1023) atomicExch(&bsum[bid], s[1023] + 1);  // flag: nonzero
    if (threadIdx.x < 64) {
        int lane = threadIdx.x;
        int val = 0;
        if (lane < bid) {
            int t;
            do { t = atomicAdd(&bsum[lane], 0); } while (t == 0);
            val = t - 1;
        }
#pragma unroll
        for (int m = 1; m < 64; m <<= 1) val += __shfl_xor(val, m, 64);
        if (lane == 0) sbase = val;
    }
    __syncthreads();
    if (i < N_NODES) {
        int o2 = s[threadIdx.x] - v + sbase;   // exclusive-in-block + block base
        offs[i] = o2;
        cursor[i] = o2;
    }
}

// ---------------- C: fused edge pass, thread-per-edge, two-pass LDS stage --------
__global__ __launch_bounds__(256) void k_edge(const int* __restrict__ src,
                                              const int* __restrict__ dst,
                                              const float* __restrict__ dis_vec,
                                              const float* __restrict__ cj,
                                              int* __restrict__ cursor,
                                              float* __restrict__ sedge,
                                              const float* __restrict__ fw1,
                                              const float* __restrict__ fw2,
                                              const float* __restrict__ fb2,
                                              float* __restrict__ outf) {
    __shared__ float buf[128 * 36];   // 18 KB
    int tid = threadIdx.x;
    int e = blockIdx.x * 256 + tid;   // grid exact: e < N_EDGES always
    // issue graph-index loads early; consumed only at the end
    int se = src[e];
    int de = dst[e];
    float cjd = cj[de];

    float dx = dis_vec[3 * e], dy = dis_vec[3 * e + 1], dz = dis_vec[3 * e + 2];
    float ax = dx + 1e-9f, ay = dy + 1e-9f, az = dz + 1e-9f;
    float dis = sqrtf(ax * ax + ay * ay + az * az);
    float x = dx + 1e-8f, y = dy + 1e-8f, z = dz + 1e-8f;
    // prefactor * PREF2, t order: (0,0,2),(0,1,1),(0,2,0),(1,0,1),(1,1,0),(2,0,0)
    float pre[6];
    pre[0] = z * z;      pre[1] = y * z * R2; pre[2] = y * y;
    pre[3] = x * z * R2; pre[4] = x * y * R2; pre[5] = x * x;

    float A = 0.f, B = 0.f;
#pragma unroll
    for (int t = 0; t < 6; t++) { A = fmaf(pre[t], pre[t], A); B += pre[t]; }
    float q[6];
#pragma unroll
    for (int tp = 0; tp < 6; tp++) {
        float s = 0.f;
#pragma unroll
        for (int t = 0; t < 6; t++) s = fmaf(pre[t], fw1[t * 6 + tp], s);
        q[tp] = s;
    }
    float bias = fb2[0];
    float w2r[6];
#pragma unroll
    for (int t = 0; t < 6; t++) w2r[t] = fw2[t];

    int b_lo = (int)ceilf((dis - HWIN) * INV_STEP);

    // window values into registers (all static indices -> stays in VGPRs)
    float os[14];
#pragma unroll
    for (int k = 0; k < 14; k++) {
        float offb = (float)((double)(b_lo + k) * STEP_D);
        float dd = dis - offb;
        float g = __expf(COEFF * dd * dd);
        float ns = fmaf(g * g, A, fmaf(2e-8f * g, B, 6e-16f));
        float rn = fast_rcp(sqrtf(ns) + 1.0f);
        float sg = g * rn;
        float o = bias;
#pragma unroll
        for (int tp = 0; tp < 6; tp++) o = fmaf(silu_f(sg * q[tp]), w2r[tp], o);
        os[k] = o;
    }

    int half = tid >> 7;        // wave-uniform: waves 0-1 -> 0, waves 2-3 -> 1
    int lrow = tid & 127;
    float4* obase = (float4*)outf + (size_t)blockIdx.x * 2048;
#pragma unroll
    for (int pass = 0; pass < 2; pass++) {
        if (half == pass) {
            float* row = &buf[lrow * 36];
            float4 b4v = make_float4(bias, bias, bias, bias);
#pragma unroll
            for (int r = 0; r < 8; r++) ((float4*)row)[r] = b4v;
#pragma unroll
            for (int k = 0; k < 14; k++) {
                int b = b_lo + k;
                if ((unsigned)b < 32u) row[b] = os[k];
            }
        }
        __syncthreads();
        // coalesced: 128 edges x 32 floats = 1024 float4, 256 threads x 4
#pragma unroll
        for (int r = 0; r < 4; r++) {
            int g = r * 256 + tid;
            int eloc = g >> 3, j = g & 7;
            obase[pass * 1024 + g] = *(const float4*)&buf[eloc * 36 + j * 4];
        }
        if (pass == 0) __syncthreads();
    }

    // ---- scatter record at the end (atomic + scattered store fire-and-forget) ----
    int p = atomicAdd(&cursor[se], 1);
    float4* op = (float4*)(sedge + (size_t)p * 8);
    op[0] = make_float4(dis, pre[0] * cjd, pre[1] * cjd, pre[2] * cjd);
    op[1] = make_float4(pre[3] * cjd, pre[4] * cjd, pre[5] * cjd, 0.f);
}

// ---------------- D: fused aggregation + msg MLP (64 nodes/block) ----------------
// Agg phase: wave wv processes 16 nodes sequentially with the PROVEN R5 inner loop
// (wave-per-node, broadcast loads, 8-edge / 16-float4 in flight). Results land in
// the LDS mi tile; barrier; msg MLP (unchanged math) consumes mi directly --
// removes the 12.8 MB msg_in HBM round-trip and one launch.
__global__ __launch_bounds__(256) void k_aggmsg(const float* __restrict__ sedge,
                                                const int* __restrict__ offs,
                                                const int* __restrict__ cnt,
                                                const float* __restrict__ w1,   // [32,128]
                                                const float* __restrict__ b1,
                                                const float* __restrict__ w2,   // [128,128]
                                                const float* __restrict__ b2,
                                                float* __restrict__ out) {
    __shared__ float mi[64 * 32];     // 8 KB msg_in tile
    __shared__ float sh[64 * 128];    // 32 KB hidden tile
    int tid = threadIdx.x;
    int wv = tid >> 6, lane = tid & 63;
    int n0 = blockIdx.x * 64;
    int b = lane >> 1, th = lane & 1;
    float offb = (float)((double)b * STEP_D);

    // prefetch (beg,deg) for this wave's 16 nodes, lane-parallel (deg=0 if OOB)
    int pn = n0 + wv * 16 + (lane & 15);
    int pbeg = 0, pdeg = 0;
    if (pn < N_NODES) { pbeg = offs[pn]; pdeg = cnt[pn]; }

    for (int u = 0; u < 16; u++) {
        int beg = __shfl(pbeg, u, 64);
        int deg = __shfl(pdeg, u, 64);
        const float4* sp = (const float4*)sedge + (size_t)beg * 2;
        float a0 = 0.f, a1 = 0.f, a2 = 0.f;
        int i = 0;
        for (; i + 8 <= deg; i += 8) {
            float4 r[16];
#pragma unroll
            for (int uu = 0; uu < 16; uu++) r[uu] = sp[uu];
            sp += 16;
#pragma unroll
            for (int uu = 0; uu < 8; uu++) {
                float4 r0 = r[2 * uu], r1 = r[2 * uu + 1];
                float dd = r0.x - offb;
                float g = __expf(COEFF * dd * dd);
                float w0 = th ? r1.x : r0.y;
                float w1v = th ? r1.y : r0.z;
                float w2v = th ? r1.z : r0.w;
                a0 = fmaf(g, w0, a0);
                a1 = fmaf(g, w1v, a1);
                a2 = fmaf(g, w2v, a2);
            }
        }
        for (; i < deg; i++) {
            float4 r0 = sp[0], r1 = sp[1];
            sp += 2;
            float dd = r0.x - offb;
            float g = __expf(COEFF * dd * dd);
            float w0 = th ? r1.x : r0.y;
            float w1v = th ? r1.y : r0.z;
            float w2v = th ? r1.z : r0.w;
            a0 = fmaf(g, w0, a0);
            a1 = fmaf(g, w1v, a1);
            a2 = fmaf(g, w2v, a2);
        }
        float s2 = a0 * a0 + a1 * a1 + a2 * a2;
        float f2 = s2 + __shfl_xor(s2, 1, 64);   // sum over all 6 t
        float p = f2 + 1e-9f;
        p = p * p;
        float tot = p;
#pragma unroll
        for (int mm = 1; mm < 64; mm <<= 1) tot += __shfl_xor(tot, mm, 64);
        float nrm = sqrtf(0.5f * tot);           // each b counted twice -> halve
        float val = f2 * fast_rcp(nrm + 1.0f);
        if (th == 0) mi[(wv * 16 + u) * 32 + b] = val;
    }
    __syncthreads();

    // ---- msg MLP on the LDS tile (identical math to old k_msg) ----
    int jq  = tid & 31;
    int ng  = tid >> 5;
    int j0  = jq * 4;

    float4 b1v = *(const float4*)&b1[j0];
    float h[8][4];
#pragma unroll
    for (int i = 0; i < 8; i++) {
        h[i][0] = b1v.x; h[i][1] = b1v.y; h[i][2] = b1v.z; h[i][3] = b1v.w;
    }
#pragma unroll
    for (int bb = 0; bb < 32; bb += 4) {
        float4 wvv[4];
#pragma unroll
        for (int u = 0; u < 4; u++) wvv[u] = *(const float4*)&w1[(bb + u) * 128 + j0];
#pragma unroll
        for (int i = 0; i < 8; i++) {
            float4 m4 = *(const float4*)&mi[(ng * 8 + i) * 32 + bb];
            h[i][0] = fmaf(m4.x, wvv[0].x, h[i][0]);
            h[i][1] = fmaf(m4.x, wvv[0].y, h[i][1]);
            h[i][2] = fmaf(m4.x, wvv[0].z, h[i][2]);
            h[i][3] = fmaf(m4.x, wvv[0].w, h[i][3]);
            h[i][0] = fmaf(m4.y, wvv[1].x, h[i][0]);
            h[i][1] = fmaf(m4.y, wvv[1].y, h[i][1]);
            h[i][2] = fmaf(m4.y, wvv[1].z, h[i][2]);
            h[i][3] = fmaf(m4.y, wvv[1].w, h[i][3]);
            h[i][0] = fmaf(m4.z, wvv[2].x, h[i][0]);
            h[i][1] = fmaf(m4.z, wvv[2].y, h[i][1]);
            h[i][2] = fmaf(m4.z, wvv[2].z, h[i][2]);
            h[i][3] = fmaf(m4.z, wvv[2].w, h[i][3]);
            h[i][0] = fmaf(m4.w, wvv[3].x, h[i][0]);
            h[i][1] = fmaf(m4.w, wvv[3].y, h[i][1]);
            h[i][2] = fmaf(m4.w, wvv[3].z, h[i][2]);
            h[i][3] = fmaf(m4.w, wvv[3].w, h[i][3]);
        }
    }
#pragma unroll
    for (int i = 0; i < 8; i++) {
        float4 sv = make_float4(silu_f(h[i][0]), silu_f(h[i][1]),
                                silu_f(h[i][2]), silu_f(h[i][3]));
        *(float4*)&sh[(ng * 8 + i) * 128 + j0] = sv;
    }
    __syncthreads();

    float4 b2v = *(const float4*)&b2[j0];
    float acc[8][4];
#pragma unroll
    for (int i = 0; i < 8; i++) {
        acc[i][0] = b2v.x; acc[i][1] = b2v.y; acc[i][2] = b2v.z; acc[i][3] = b2v.w;
    }
    for (int hb = 0; hb < 128; hb += 4) {
        float4 wvv[4];
#pragma unroll
        for (int u = 0; u < 4; u++) wvv[u] = *(const float4*)&w2[(hb + u) * 128 + j0];
#pragma unroll
        for (int i = 0; i < 8; i++) {
            float4 s4 = *(const float4*)&sh[(ng * 8 + i) * 128 + hb];
            acc[i][0] = fmaf(s4.x, wvv[0].x, acc[i][0]);
            acc[i][1] = fmaf(s4.x, wvv[0].y, acc[i][1]);
            acc[i][2] = fmaf(s4.x, wvv[0].z, acc[i][2]);
            acc[i][3] = fmaf(s4.x, wvv[0].w, acc[i][3]);
            acc[i][0] = fmaf(s4.y, wvv[1].x, acc[i][0]);
            acc[i][1] = fmaf(s4.y, wvv[1].y, acc[i][1]);
            acc[i][2] = fmaf(s4.y, wvv[1].z, acc[i][2]);
            acc[i][3] = fmaf(s4.y, wvv[1].w, acc[i][3]);
            acc[i][0] = fmaf(s4.z, wvv[2].x, acc[i][0]);
            acc[i][1] = fmaf(s4.z, wvv[2].y, acc[i][1]);
            acc[i][2] = fmaf(s4.z, wvv[2].z, acc[i][2]);
            acc[i][3] = fmaf(s4.z, wvv[2].w, acc[i][3]);
            acc[i][0] = fmaf(s4.w, wvv[3].x, acc[i][0]);
            acc[i][1] = fmaf(s4.w, wvv[3].y, acc[i][1]);
            acc[i][2] = fmaf(s4.w, wvv[3].z, acc[i][2]);
            acc[i][3] = fmaf(s4.w, wvv[3].w, acc[i][3]);
        }
    }
#pragma unroll
    for (int i = 0; i < 8; i++) {
        int n = n0 + ng * 8 + i;
        if (n < N_NODES) {
            *(float4*)&out[(size_t)n * 128 + j0] =
                make_float4(acc[i][0], acc[i][1], acc[i][2], acc[i][3]);
        }
    }
}

extern "C" void kernel_launch(void* const* d_in, const int* in_sizes, int n_in,
                              void* d_out, int out_size, void* d_ws, size_t ws_size,
                              hipStream_t stream) {
    (void)in_sizes; (void)n_in; (void)out_size; (void)ws_size;
    const float* feat    = (const float*)d_in[0];
    const float* dis_vec = (const float*)d_in[1];
    const float* cj_w1   = (const float*)d_in[2];
    const float* cj_b1   = (const float*)d_in[3];
    const float* cj_w2   = (const float*)d_in[4];
    const float* cj_b2   = (const float*)d_in[5];
    const float* msg_w1  = (const float*)d_in[6];
    const float* msg_b1  = (const float*)d_in[7];
    const float* msg_w2  = (const float*)d_in[8];
    const float* msg_b2  = (const float*)d_in[9];
    const float* filt_w1 = (const float*)d_in[10];
    const float* filt_w2 = (const float*)d_in[11];
    const float* filt_b2 = (const float*)d_in[12];
    const int*   src     = (const int*)d_in[13];
    const int*   dst     = (const int*)d_in[14];
    float* out = (float*)d_out;

    // workspace layout (elements), all 16B aligned; cnt+bsum zeroed in one memset
    float* ws     = (float*)d_ws;
    float* cj     = ws;                        // 50048 floats
    int*   cnt    = (int*)(cj + 50048);        // 50048 ints (zeroed)
    int*   bsum   = cnt + 50048;               // 64 ints   (zeroed)
    int*   offs   = bsum + 64;                 // 50048 ints
    int*   cursor = offs + 50048;              // 50048 ints
    float* sedge  = (float*)(cursor + 50048);  // 6400000 floats (25.6 MB)

    hipMemsetAsync(cnt, 0, (50048 + 64) * sizeof(int), stream);

    k_cj_count<<<CJ_BLOCKS + CNT_BLOCKS, 256, 0, stream>>>(feat, cj_w1, cj_b1, cj_w2,
                                                           cj_b2, cj, src, cnt);
    k_scan<<<SCAN_BLOCKS, 1024, 0, stream>>>(cnt, offs, cursor, bsum);
    k_edge<<<EDGE_BLOCKS, 256, 0, stream>>>(src, dst, dis_vec, cj, cursor, sedge,
                                            filt_w1, filt_w2, filt_b2,
                                            out + (size_t)N_NODES * NA);
    k_aggmsg<<<AGG_BLOCKS, 256, 0, stream>>>(sedge, offs, cnt,
                                             msg_w1, msg_b1, msg_w2, msg_b2, out);
}

// Round 9
// 368.383 us; speedup vs baseline: 1.0155x; 1.0155x over previous
//
#include <hip/hip_runtime.h>
#include <math.h>

#define N_NODES 50000
#define N_EDGES 800000
#define NB 32
#define NA 128
#define CJ_BLOCKS 782           // (N_NODES+63)/64
#define CNT_BLOCKS 3125         // N_EDGES/256 exactly
#define EDGE_BLOCKS 3125        // N_EDGES/256 exactly
#define SCAN_BLOCKS 49          // ceil(N_NODES/1024)

constexpr double STEP_D = 10.0 / 31.0;
constexpr float  STEP_F = (float)(10.0 / 31.0);       // matches np.float32 width
constexpr float  COEFF  = -0.5f / (STEP_F * STEP_F);  // -0.5/width^2
constexpr float  R2     = 1.41421356237309515f;       // sqrt(2) = PREF2 for mixed terms
constexpr float  INV_STEP = 3.1f;                     // 31/10
constexpr float  HWIN   = 2.05f;                      // g(HWIN) ~ 1.7e-9

__device__ __forceinline__ float fast_rcp(float x) {
    return __builtin_amdgcn_rcpf(x);   // v_rcp_f32, ~1ulp
}

__device__ __forceinline__ float silu_f(float x) {
    return x * fast_rcp(1.0f + __expf(-x));
}

// ---------------- A1: cj = MLP(feat) -> [N] scalar (64 nodes/block) --------------
__global__ __launch_bounds__(256) void k_cj(const float* __restrict__ feat,
                                            const float* __restrict__ w1,
                                            const float* __restrict__ b1,
                                            const float* __restrict__ w2,
                                            const float* __restrict__ b2,
                                            float* __restrict__ cj) {
    __shared__ float fls[64 * 128];   // 32 KB feat tile
    int tid = threadIdx.x;
    int jq  = tid & 31;          // j quad: j0 = 4*jq
    int ng  = tid >> 5;          // node group 0..7 (8 nodes each)
    int j0  = jq * 4;
    int n0  = blockIdx.x * 64;

    // stage feat tile (coalesced float4, clamped for tail block)
    {
        const float4* fp = (const float4*)feat;
        int base = n0 * 32;                    // float4 index
        int maxi = N_NODES * 32 - 1;
#pragma unroll
        for (int r = 0; r < 8; r++) {
            int idx = base + r * 256 + tid;
            ((float4*)fls)[r * 256 + tid] = fp[min(idx, maxi)];
        }
    }
    __syncthreads();

    float4 bv = *(const float4*)&b1[j0];
    float h[8][4];
#pragma unroll
    for (int i = 0; i < 8; i++) {
        h[i][0] = bv.x; h[i][1] = bv.y; h[i][2] = bv.z; h[i][3] = bv.w;
    }
    for (int kb = 0; kb < 128; kb += 4) {
        float4 wv[4];
#pragma unroll
        for (int u = 0; u < 4; u++) wv[u] = *(const float4*)&w1[(kb + u) * 128 + j0];
#pragma unroll
        for (int i = 0; i < 8; i++) {
            float4 f4 = *(const float4*)&fls[(ng * 8 + i) * 128 + kb];
            h[i][0] = fmaf(f4.x, wv[0].x, h[i][0]);
            h[i][1] = fmaf(f4.x, wv[0].y, h[i][1]);
            h[i][2] = fmaf(f4.x, wv[0].z, h[i][2]);
            h[i][3] = fmaf(f4.x, wv[0].w, h[i][3]);
            h[i][0] = fmaf(f4.y, wv[1].x, h[i][0]);
            h[i][1] = fmaf(f4.y, wv[1].y, h[i][1]);
            h[i][2] = fmaf(f4.y, wv[1].z, h[i][2]);
            h[i][3] = fmaf(f4.y, wv[1].w, h[i][3]);
            h[i][0] = fmaf(f4.z, wv[2].x, h[i][0]);
            h[i][1] = fmaf(f4.z, wv[2].y, h[i][1]);
            h[i][2] = fmaf(f4.z, wv[2].z, h[i][2]);
            h[i][3] = fmaf(f4.z, wv[2].w, h[i][3]);
            h[i][0] = fmaf(f4.w, wv[3].x, h[i][0]);
            h[i][1] = fmaf(f4.w, wv[3].y, h[i][1]);
            h[i][2] = fmaf(f4.w, wv[3].z, h[i][2]);
            h[i][3] = fmaf(f4.w, wv[3].w, h[i][3]);
        }
    }
    // epilogue: cj[n] = b2 + sum_j silu(h)*w2[j]; reduce across the 32-lane jq group
    float4 w2v = *(const float4*)&w2[j0];
    float keep = 0.f;
#pragma unroll
    for (int i = 0; i < 8; i++) {
        float v = silu_f(h[i][0]) * w2v.x + silu_f(h[i][1]) * w2v.y
                + silu_f(h[i][2]) * w2v.z + silu_f(h[i][3]) * w2v.w;
#pragma unroll
        for (int m = 1; m < 32; m <<= 1) v += __shfl_xor(v, m, 64);
        if (jq == i) keep = v;
    }
    if (jq < 8) {
        int n = n0 + ng * 8 + jq;
        if (n < N_NODES) cj[n] = b2[0] + keep;
    }
}

// ---------------- A2: count edges per src node -----------------------------------
__global__ void k_count(const int* __restrict__ src, int* __restrict__ cnt) {
    int e = blockIdx.x * 256 + threadIdx.x;
    if (e < N_EDGES) atomicAdd(&cnt[src[e]], 1);
}

// ---------------- B: single-kernel scan (49 co-resident blocks, flag sync) -------
__global__ __launch_bounds__(1024) void k_scan(const int* __restrict__ cnt,
                                               int* __restrict__ offs,
                                               int* __restrict__ cursor,
                                               int* __restrict__ bsum) {
    __shared__ int s[1024];
    __shared__ int sbase;
    int bid = blockIdx.x;
    int i = bid * 1024 + threadIdx.x;
    int v = (i < N_NODES) ? cnt[i] : 0;
    s[threadIdx.x] = v;
    __syncthreads();
    for (int o = 1; o < 1024; o <<= 1) {
        int t = (threadIdx.x >= (unsigned)o) ? s[threadIdx.x - o] : 0;
        __syncthreads();
        s[threadIdx.x] += t;
        __syncthreads();
    }
    if (threadIdx.x == 1023) atomicExch(&bsum[bid], s[1023] + 1);  // flag: nonzero
    if (threadIdx.x < 64) {
        int lane = threadIdx.x;
        int val = 0;
        if (lane < bid) {
            int t;
            do { t = atomicAdd(&bsum[lane], 0); } while (t == 0);
            val = t - 1;
        }
#pragma unroll
        for (int m = 1; m < 64; m <<= 1) val += __shfl_xor(val, m, 64);
        if (lane == 0) sbase = val;
    }
    __syncthreads();
    if (i < N_NODES) {
        int o2 = s[threadIdx.x] - v + sbase;   // exclusive-in-block + block base
        offs[i] = o2;
        cursor[i] = o2;
    }
}

// ---------------- C: fused edge pass, thread-per-edge, two-pass LDS stage --------
__global__ __launch_bounds__(256) void k_edge(const int* __restrict__ src,
                                              const int* __restrict__ dst,
                                              const float* __restrict__ dis_vec,
                                              const float* __restrict__ cj,
                                              int* __restrict__ cursor,
                                              float* __restrict__ sedge,
                                              const float* __restrict__ fw1,
                                              const float* __restrict__ fw2,
                                              const float* __restrict__ fb2,
                                              float* __restrict__ outf) {
    __shared__ float buf[128 * 36];   // 18 KB
    int tid = threadIdx.x;
    int e = blockIdx.x * 256 + tid;   // grid exact: e < N_EDGES always
    // issue graph-index loads early; consumed only at the end
    int se = src[e];
    int de = dst[e];
    float cjd = cj[de];

    float dx = dis_vec[3 * e], dy = dis_vec[3 * e + 1], dz = dis_vec[3 * e + 2];
    float ax = dx + 1e-9f, ay = dy + 1e-9f, az = dz + 1e-9f;
    float dis = sqrtf(ax * ax + ay * ay + az * az);
    float x = dx + 1e-8f, y = dy + 1e-8f, z = dz + 1e-8f;
    // prefactor * PREF2, t order: (0,0,2),(0,1,1),(0,2,0),(1,0,1),(1,1,0),(2,0,0)
    float pre[6];
    pre[0] = z * z;      pre[1] = y * z * R2; pre[2] = y * y;
    pre[3] = x * z * R2; pre[4] = x * y * R2; pre[5] = x * x;

    float A = 0.f, B = 0.f;
#pragma unroll
    for (int t = 0; t < 6; t++) { A = fmaf(pre[t], pre[t], A); B += pre[t]; }
    float q[6];
#pragma unroll
    for (int tp = 0; tp < 6; tp++) {
        float s = 0.f;
#pragma unroll
        for (int t = 0; t < 6; t++) s = fmaf(pre[t], fw1[t * 6 + tp], s);
        q[tp] = s;
    }
    float bias = fb2[0];
    float w2r[6];
#pragma unroll
    for (int t = 0; t < 6; t++) w2r[t] = fw2[t];

    int b_lo = (int)ceilf((dis - HWIN) * INV_STEP);

    // window values into registers (all static indices -> stays in VGPRs)
    float os[14];
#pragma unroll
    for (int k = 0; k < 14; k++) {
        float offb = (float)((double)(b_lo + k) * STEP_D);
        float dd = dis - offb;
        float g = __expf(COEFF * dd * dd);
        float ns = fmaf(g * g, A, fmaf(2e-8f * g, B, 6e-16f));
        float rn = fast_rcp(sqrtf(ns) + 1.0f);
        float sg = g * rn;
        float o = bias;
#pragma unroll
        for (int tp = 0; tp < 6; tp++) o = fmaf(silu_f(sg * q[tp]), w2r[tp], o);
        os[k] = o;
    }

    int half = tid >> 7;        // wave-uniform: waves 0-1 -> 0, waves 2-3 -> 1
    int lrow = tid & 127;
    float4* obase = (float4*)outf + (size_t)blockIdx.x * 2048;
#pragma unroll
    for (int pass = 0; pass < 2; pass++) {
        if (half == pass) {
            float* row = &buf[lrow * 36];
            float4 b4v = make_float4(bias, bias, bias, bias);
#pragma unroll
            for (int r = 0; r < 8; r++) ((float4*)row)[r] = b4v;
#pragma unroll
            for (int k = 0; k < 14; k++) {
                int b = b_lo + k;
                if ((unsigned)b < 32u) row[b] = os[k];
            }
        }
        __syncthreads();
        // coalesced: 128 edges x 32 floats = 1024 float4, 256 threads x 4
#pragma unroll
        for (int r = 0; r < 4; r++) {
            int g = r * 256 + tid;
            int eloc = g >> 3, j = g & 7;
            obase[pass * 1024 + g] = *(const float4*)&buf[eloc * 36 + j * 4];
        }
        if (pass == 0) __syncthreads();
    }

    // ---- scatter record at the end (atomic + scattered store fire-and-forget) ----
    int p = atomicAdd(&cursor[se], 1);
    float4* op = (float4*)(sedge + (size_t)p * 8);
    op[0] = make_float4(dis, pre[0] * cjd, pre[1] * cjd, pre[2] * cjd);
    op[1] = make_float4(pre[3] * cjd, pre[4] * cjd, pre[5] * cjd, 0.f);
}

// ---------------- D: per-node aggregation, 8 edges (16 float4) in flight ---------
__global__ __launch_bounds__(256) void k_agg(const float* __restrict__ sedge,
                                             const int* __restrict__ offs,
                                             const int* __restrict__ cnt,
                                             float* __restrict__ msg_in) {
    int lane = threadIdx.x & 63;
    int n = blockIdx.x * 4 + (threadIdx.x >> 6);
    if (n >= N_NODES) return;
    int b = lane >> 1, th = lane & 1;
    float offb = (float)((double)b * STEP_D);
    int beg = offs[n];
    int deg = cnt[n];
    const float4* sp = (const float4*)sedge + (size_t)beg * 2;
    float a0 = 0.f, a1 = 0.f, a2 = 0.f;
    int i = 0;
    for (; i + 8 <= deg; i += 8) {
        float4 r[16];
#pragma unroll
        for (int u = 0; u < 16; u++) r[u] = sp[u];
        sp += 16;
#pragma unroll
        for (int u = 0; u < 8; u++) {
            float4 r0 = r[2 * u], r1 = r[2 * u + 1];
            float dd = r0.x - offb;
            float g = __expf(COEFF * dd * dd);
            float w0 = th ? r1.x : r0.y;
            float w1 = th ? r1.y : r0.z;
            float w2 = th ? r1.z : r0.w;
            a0 = fmaf(g, w0, a0);
            a1 = fmaf(g, w1, a1);
            a2 = fmaf(g, w2, a2);
        }
    }
    for (; i < deg; i++) {
        float4 r0 = sp[0], r1 = sp[1];
        sp += 2;
        float dd = r0.x - offb;
        float g = __expf(COEFF * dd * dd);
        float w0 = th ? r1.x : r0.y;
        float w1 = th ? r1.y : r0.z;
        float w2 = th ? r1.z : r0.w;
        a0 = fmaf(g, w0, a0);
        a1 = fmaf(g, w1, a1);
        a2 = fmaf(g, w2, a2);
    }
    float s = a0 * a0 + a1 * a1 + a2 * a2;
    float f2 = s + __shfl_xor(s, 1, 64);  // sum over all 6 t
    float p = f2 + 1e-9f;
    p = p * p;
    float tot = p;
#pragma unroll
    for (int m = 1; m < 64; m <<= 1) tot += __shfl_xor(tot, m, 64);
    // each b counted twice (both th lanes) -> halve
    float nrm = sqrtf(0.5f * tot);
    float val = f2 * fast_rcp(nrm + 1.0f);
    if (th == 0) msg_in[(size_t)n * NB + b] = val;
}

// ---------------- E: msg MLP (64 nodes/block, thread = 4 j x 8 nodes) ------------
__global__ __launch_bounds__(256) void k_msg(const float* __restrict__ msg_in,
                                             const float* __restrict__ w1,   // [32,128]
                                             const float* __restrict__ b1,
                                             const float* __restrict__ w2,   // [128,128]
                                             const float* __restrict__ b2,
                                             float* __restrict__ out) {
    __shared__ float mi[64 * 32];     // 8 KB input tile
    __shared__ float sh[64 * 128];    // 32 KB hidden tile
    int tid = threadIdx.x;
    int jq  = tid & 31;
    int ng  = tid >> 5;
    int j0  = jq * 4;
    int n0  = blockIdx.x * 64;

    // stage msg_in tile (64 nodes x 32 basis = 2048 floats)
    {
        const float4* srcp = (const float4*)msg_in;
        int base = n0 * 8;
        int maxi = N_NODES * 8 - 1;
#pragma unroll
        for (int r = 0; r < 2; r++) {
            int idx = base + r * 256 + tid;
            ((float4*)mi)[r * 256 + tid] = srcp[min(idx, maxi)];
        }
    }
    __syncthreads();

    float4 b1v = *(const float4*)&b1[j0];
    float h[8][4];
#pragma unroll
    for (int i = 0; i < 8; i++) {
        h[i][0] = b1v.x; h[i][1] = b1v.y; h[i][2] = b1v.z; h[i][3] = b1v.w;
    }
#pragma unroll
    for (int bb = 0; bb < 32; bb += 4) {
        float4 wv[4];
#pragma unroll
        for (int u = 0; u < 4; u++) wv[u] = *(const float4*)&w1[(bb + u) * 128 + j0];
#pragma unroll
        for (int i = 0; i < 8; i++) {
            float4 m4 = *(const float4*)&mi[(ng * 8 + i) * 32 + bb];
            h[i][0] = fmaf(m4.x, wv[0].x, h[i][0]);
            h[i][1] = fmaf(m4.x, wv[0].y, h[i][1]);
            h[i][2] = fmaf(m4.x, wv[0].z, h[i][2]);
            h[i][3] = fmaf(m4.x, wv[0].w, h[i][3]);
            h[i][0] = fmaf(m4.y, wv[1].x, h[i][0]);
            h[i][1] = fmaf(m4.y, wv[1].y, h[i][1]);
            h[i][2] = fmaf(m4.y, wv[1].z, h[i][2]);
            h[i][3] = fmaf(m4.y, wv[1].w, h[i][3]);
            h[i][0] = fmaf(m4.z, wv[2].x, h[i][0]);
            h[i][1] = fmaf(m4.z, wv[2].y, h[i][1]);
            h[i][2] = fmaf(m4.z, wv[2].z, h[i][2]);
            h[i][3] = fmaf(m4.z, wv[2].w, h[i][3]);
            h[i][0] = fmaf(m4.w, wv[3].x, h[i][0]);
            h[i][1] = fmaf(m4.w, wv[3].y, h[i][1]);
            h[i][2] = fmaf(m4.w, wv[3].z, h[i][2]);
            h[i][3] = fmaf(m4.w, wv[3].w, h[i][3]);
        }
    }
#pragma unroll
    for (int i = 0; i < 8; i++) {
        float4 sv = make_float4(silu_f(h[i][0]), silu_f(h[i][1]),
                                silu_f(h[i][2]), silu_f(h[i][3]));
        *(float4*)&sh[(ng * 8 + i) * 128 + j0] = sv;
    }
    __syncthreads();

    float4 b2v = *(const float4*)&b2[j0];
    float acc[8][4];
#pragma unroll
    for (int i = 0; i < 8; i++) {
        acc[i][0] = b2v.x; acc[i][1] = b2v.y; acc[i][2] = b2v.z; acc[i][3] = b2v.w;
    }
    for (int hb = 0; hb < 128; hb += 4) {
        float4 wv[4];
#pragma unroll
        for (int u = 0; u < 4; u++) wv[u] = *(const float4*)&w2[(hb + u) * 128 + j0];
#pragma unroll
        for (int i = 0; i < 8; i++) {
            float4 s4 = *(const float4*)&sh[(ng * 8 + i) * 128 + hb];
            acc[i][0] = fmaf(s4.x, wv[0].x, acc[i][0]);
            acc[i][1] = fmaf(s4.x, wv[0].y, acc[i][1]);
            acc[i][2] = fmaf(s4.x, wv[0].z, acc[i][2]);
            acc[i][3] = fmaf(s4.x, wv[0].w, acc[i][3]);
            acc[i][0] = fmaf(s4.y, wv[1].x, acc[i][0]);
            acc[i][1] = fmaf(s4.y, wv[1].y, acc[i][1]);
            acc[i][2] = fmaf(s4.y, wv[1].z, acc[i][2]);
            acc[i][3] = fmaf(s4.y, wv[1].w, acc[i][3]);
            acc[i][0] = fmaf(s4.z, wv[2].x, acc[i][0]);
            acc[i][1] = fmaf(s4.z, wv[2].y, acc[i][1]);
            acc[i][2] = fmaf(s4.z, wv[2].z, acc[i][2]);
            acc[i][3] = fmaf(s4.z, wv[2].w, acc[i][3]);
            acc[i][0] = fmaf(s4.w, wv[3].x, acc[i][0]);
            acc[i][1] = fmaf(s4.w, wv[3].y, acc[i][1]);
            acc[i][2] = fmaf(s4.w, wv[3].z, acc[i][2]);
            acc[i][3] = fmaf(s4.w, wv[3].w, acc[i][3]);
        }
    }
#pragma unroll
    for (int i = 0; i < 8; i++) {
        int n = n0 + ng * 8 + i;
        if (n < N_NODES) {
            *(float4*)&out[(size_t)n * 128 + j0] =
                make_float4(acc[i][0], acc[i][1], acc[i][2], acc[i][3]);
        }
    }
}

extern "C" void kernel_launch(void* const* d_in, const int* in_sizes, int n_in,
                              void* d_out, int out_size, void* d_ws, size_t ws_size,
                              hipStream_t stream) {
    (void)in_sizes; (void)n_in; (void)out_size; (void)ws_size;
    const float* feat    = (const float*)d_in[0];
    const float* dis_vec = (const float*)d_in[1];
    const float* cj_w1   = (const float*)d_in[2];
    const float* cj_b1   = (const float*)d_in[3];
    const float* cj_w2   = (const float*)d_in[4];
    const float* cj_b2   = (const float*)d_in[5];
    const float* msg_w1  = (const float*)d_in[6];
    const float* msg_b1  = (const float*)d_in[7];
    const float* msg_w2  = (const float*)d_in[8];
    const float* msg_b2  = (const float*)d_in[9];
    const float* filt_w1 = (const float*)d_in[10];
    const float* filt_w2 = (const float*)d_in[11];
    const float* filt_b2 = (const float*)d_in[12];
    const int*   src     = (const int*)d_in[13];
    const int*   dst     = (const int*)d_in[14];
    float* out = (float*)d_out;

    // workspace layout (elements), all 16B aligned; cnt+bsum zeroed in one memset
    float* ws     = (float*)d_ws;
    float* cj     = ws;                        // 50048 floats
    int*   cnt    = (int*)(cj + 50048);        // 50048 ints (zeroed)
    int*   bsum   = cnt + 50048;               // 64 ints   (zeroed)
    int*   offs   = bsum + 64;                 // 50048 ints
    int*   cursor = offs + 50048;              // 50048 ints
    float* msg_in = (float*)(cursor + 50048);  // 1600256 floats
    float* sedge  = msg_in + 1600256;          // 6400000 floats (25.6 MB)

    hipMemsetAsync(cnt, 0, (50048 + 64) * sizeof(int), stream);

    k_count<<<CNT_BLOCKS, 256, 0, stream>>>(src, cnt);
    k_cj<<<CJ_BLOCKS, 256, 0, stream>>>(feat, cj_w1, cj_b1, cj_w2, cj_b2, cj);
    k_scan<<<SCAN_BLOCKS, 1024, 0, stream>>>(cnt, offs, cursor, bsum);
    k_edge<<<EDGE_BLOCKS, 256, 0, stream>>>(src, dst, dis_vec, cj, cursor, sedge,
                                            filt_w1, filt_w2, filt_b2,
                                            out + (size_t)N_NODES * NA);
    k_agg<<<(N_NODES + 3) / 4, 256, 0, stream>>>(sedge, offs, cnt, msg_in);
    k_msg<<<(N_NODES + 63) / 64, 256, 0, stream>>>(msg_in, msg_w1, msg_b1, msg_w2, msg_b2, out);
}

// Round 10
// 355.404 us; speedup vs baseline: 1.0526x; 1.0365x over previous
//
#include <hip/hip_runtime.h>
#include <math.h>

#define N_NODES 50000
#define N_EDGES 800000
#define NB 32
#define NA 128
#define CJ_BLOCKS 782           // (N_NODES+63)/64
#define CNT_BLOCKS4 782         // ceil(N_EDGES/1024), 4 edges/thread
#define EDGE_BLOCKS 3125        // N_EDGES/256 exactly
#define SCAN_BLOCKS 49          // ceil(N_NODES/1024)

constexpr double STEP_D = 10.0 / 31.0;
constexpr float  STEP_F = (float)(10.0 / 31.0);       // matches np.float32 width
constexpr float  COEFF  = -0.5f / (STEP_F * STEP_F);  // -0.5/width^2
constexpr float  R2     = 1.41421356237309515f;       // sqrt(2) = PREF2 for mixed terms
constexpr float  INV_STEP = 3.1f;                     // 31/10
constexpr float  HWIN   = 2.05f;                      // g(HWIN) ~ 1.7e-9

__device__ __forceinline__ float fast_rcp(float x) {
    return __builtin_amdgcn_rcpf(x);   // v_rcp_f32, ~1ulp
}

__device__ __forceinline__ float silu_f(float x) {
    return x * fast_rcp(1.0f + __expf(-x));
}

// ---------------- A: fused cj-MLP (blocks < CJ_BLOCKS) + edge count (rest) --------
// count part: 4 edges/thread via int4 (1/4 the blocks and index loads vs scalar).
__global__ __launch_bounds__(256) void k_cj_count(const float* __restrict__ feat,
                                                  const float* __restrict__ w1,
                                                  const float* __restrict__ b1,
                                                  const float* __restrict__ w2,
                                                  const float* __restrict__ b2,
                                                  float* __restrict__ cj,
                                                  const int* __restrict__ src,
                                                  int* __restrict__ cnt) {
    __shared__ float fls[64 * 128];   // 32 KB feat tile (unused by count blocks)
    int tid = threadIdx.x;
    int blk = blockIdx.x;
    if (blk >= CJ_BLOCKS) {
        int base = (blk - CJ_BLOCKS) * 1024 + tid * 4;
        if (base + 3 < N_EDGES) {
            int4 s4 = *(const int4*)&src[base];
            atomicAdd(&cnt[s4.x], 1);
            atomicAdd(&cnt[s4.y], 1);
            atomicAdd(&cnt[s4.z], 1);
            atomicAdd(&cnt[s4.w], 1);
        } else {
#pragma unroll
            for (int u = 0; u < 4; u++) {
                int e = base + u;
                if (e < N_EDGES) atomicAdd(&cnt[src[e]], 1);
            }
        }
        return;
    }
    int jq  = tid & 31;          // j quad: j0 = 4*jq
    int ng  = tid >> 5;          // node group 0..7 (8 nodes each)
    int j0  = jq * 4;
    int n0  = blk * 64;

    // stage feat tile (coalesced float4, clamped for tail block)
    {
        const float4* fp = (const float4*)feat;
        int base = n0 * 32;                    // float4 index
        int maxi = N_NODES * 32 - 1;
#pragma unroll
        for (int r = 0; r < 8; r++) {
            int idx = base + r * 256 + tid;
            ((float4*)fls)[r * 256 + tid] = fp[min(idx, maxi)];
        }
    }
    __syncthreads();

    float4 bv = *(const float4*)&b1[j0];
    float h[8][4];
#pragma unroll
    for (int i = 0; i < 8; i++) {
        h[i][0] = bv.x; h[i][1] = bv.y; h[i][2] = bv.z; h[i][3] = bv.w;
    }
    for (int kb = 0; kb < 128; kb += 4) {
        float4 wv[4];
#pragma unroll
        for (int u = 0; u < 4; u++) wv[u] = *(const float4*)&w1[(kb + u) * 128 + j0];
#pragma unroll
        for (int i = 0; i < 8; i++) {
            float4 f4 = *(const float4*)&fls[(ng * 8 + i) * 128 + kb];
            h[i][0] = fmaf(f4.x, wv[0].x, h[i][0]);
            h[i][1] = fmaf(f4.x, wv[0].y, h[i][1]);
            h[i][2] = fmaf(f4.x, wv[0].z, h[i][2]);
            h[i][3] = fmaf(f4.x, wv[0].w, h[i][3]);
            h[i][0] = fmaf(f4.y, wv[1].x, h[i][0]);
            h[i][1] = fmaf(f4.y, wv[1].y, h[i][1]);
            h[i][2] = fmaf(f4.y, wv[1].z, h[i][2]);
            h[i][3] = fmaf(f4.y, wv[1].w, h[i][3]);
            h[i][0] = fmaf(f4.z, wv[2].x, h[i][0]);
            h[i][1] = fmaf(f4.z, wv[2].y, h[i][1]);
            h[i][2] = fmaf(f4.z, wv[2].z, h[i][2]);
            h[i][3] = fmaf(f4.z, wv[2].w, h[i][3]);
            h[i][0] = fmaf(f4.w, wv[3].x, h[i][0]);
            h[i][1] = fmaf(f4.w, wv[3].y, h[i][1]);
            h[i][2] = fmaf(f4.w, wv[3].z, h[i][2]);
            h[i][3] = fmaf(f4.w, wv[3].w, h[i][3]);
        }
    }
    // epilogue: cj[n] = b2 + sum_j silu(h)*w2[j]; reduce across the 32-lane jq group
    float4 w2v = *(const float4*)&w2[j0];
    float keep = 0.f;
#pragma unroll
    for (int i = 0; i < 8; i++) {
        float v = silu_f(h[i][0]) * w2v.x + silu_f(h[i][1]) * w2v.y
                + silu_f(h[i][2]) * w2v.z + silu_f(h[i][3]) * w2v.w;
#pragma unroll
        for (int m = 1; m < 32; m <<= 1) v += __shfl_xor(v, m, 64);
        if (jq == i) keep = v;
    }
    if (jq < 8) {
        int n = n0 + ng * 8 + jq;
        if (n < N_NODES) cj[n] = b2[0] + keep;
    }
}

// ---------------- B: single-kernel scan (49 co-resident blocks, flag sync) -------
__global__ __launch_bounds__(1024) void k_scan(const int* __restrict__ cnt,
                                               int* __restrict__ offs,
                                               int* __restrict__ cursor,
                                               int* __restrict__ bsum) {
    __shared__ int s[1024];
    __shared__ int sbase;
    int bid = blockIdx.x;
    int i = bid * 1024 + threadIdx.x;
    int v = (i < N_NODES) ? cnt[i] : 0;
    s[threadIdx.x] = v;
    __syncthreads();
    for (int o = 1; o < 1024; o <<= 1) {
        int t = (threadIdx.x >= (unsigned)o) ? s[threadIdx.x - o] : 0;
        __syncthreads();
        s[threadIdx.x] += t;
        __syncthreads();
    }
    if (threadIdx.x == 1023) atomicExch(&bsum[bid], s[1023] + 1);  // flag: nonzero
    if (threadIdx.x < 64) {
        int lane = threadIdx.x;
        int val = 0;
        if (lane < bid) {
            int t;
            do { t = atomicAdd(&bsum[lane], 0); } while (t == 0);
            val = t - 1;
        }
#pragma unroll
        for (int m = 1; m < 64; m <<= 1) val += __shfl_xor(val, m, 64);
        if (lane == 0) sbase = val;
    }
    __syncthreads();
    if (i < N_NODES) {
        int o2 = s[threadIdx.x] - v + sbase;   // exclusive-in-block + block base
        offs[i] = o2;
        cursor[i] = o2;
    }
}

// ---------------- C: fused edge pass, thread-per-edge, two-pass LDS stage --------
__global__ __launch_bounds__(256) void k_edge(const int* __restrict__ src,
                                              const int* __restrict__ dst,
                                              const float* __restrict__ dis_vec,
                                              const float* __restrict__ cj,
                                              int* __restrict__ cursor,
                                              float* __restrict__ sedge,
                                              const float* __restrict__ fw1,
                                              const float* __restrict__ fw2,
                                              const float* __restrict__ fb2,
                                              float* __restrict__ outf) {
    __shared__ float buf[128 * 36];   // 18 KB
    int tid = threadIdx.x;
    int e = blockIdx.x * 256 + tid;   // grid exact: e < N_EDGES always
    // issue graph-index loads early; consumed only at the end
    int se = src[e];
    int de = dst[e];
    float cjd = cj[de];

    float dx = dis_vec[3 * e], dy = dis_vec[3 * e + 1], dz = dis_vec[3 * e + 2];
    float ax = dx + 1e-9f, ay = dy + 1e-9f, az = dz + 1e-9f;
    float dis = sqrtf(ax * ax + ay * ay + az * az);
    float x = dx + 1e-8f, y = dy + 1e-8f, z = dz + 1e-8f;
    // prefactor * PREF2, t order: (0,0,2),(0,1,1),(0,2,0),(1,0,1),(1,1,0),(2,0,0)
    float pre[6];
    pre[0] = z * z;      pre[1] = y * z * R2; pre[2] = y * y;
    pre[3] = x * z * R2; pre[4] = x * y * R2; pre[5] = x * x;

    float A = 0.f, B = 0.f;
#pragma unroll
    for (int t = 0; t < 6; t++) { A = fmaf(pre[t], pre[t], A); B += pre[t]; }
    float q[6];
#pragma unroll
    for (int tp = 0; tp < 6; tp++) {
        float s = 0.f;
#pragma unroll
        for (int t = 0; t < 6; t++) s = fmaf(pre[t], fw1[t * 6 + tp], s);
        q[tp] = s;
    }
    float bias = fb2[0];
    float w2r[6];
#pragma unroll
    for (int t = 0; t < 6; t++) w2r[t] = fw2[t];

    int b_lo = (int)ceilf((dis - HWIN) * INV_STEP);

    // window values into registers (all static indices -> stays in VGPRs)
    float os[14];
#pragma unroll
    for (int k = 0; k < 14; k++) {
        float offb = (float)((double)(b_lo + k) * STEP_D);
        float dd = dis - offb;
        float g = __expf(COEFF * dd * dd);
        float ns = fmaf(g * g, A, fmaf(2e-8f * g, B, 6e-16f));
        float rn = fast_rcp(sqrtf(ns) + 1.0f);
        float sg = g * rn;
        float o = bias;
#pragma unroll
        for (int tp = 0; tp < 6; tp++) o = fmaf(silu_f(sg * q[tp]), w2r[tp], o);
        os[k] = o;
    }

    int half = tid >> 7;        // wave-uniform: waves 0-1 -> 0, waves 2-3 -> 1
    int lrow = tid & 127;
    float4* obase = (float4*)outf + (size_t)blockIdx.x * 2048;
#pragma unroll
    for (int pass = 0; pass < 2; pass++) {
        if (half == pass) {
            float* row = &buf[lrow * 36];
            float4 b4v = make_float4(bias, bias, bias, bias);
#pragma unroll
            for (int r = 0; r < 8; r++) ((float4*)row)[r] = b4v;
#pragma unroll
            for (int k = 0; k < 14; k++) {
                int b = b_lo + k;
                if ((unsigned)b < 32u) row[b] = os[k];
            }
        }
        __syncthreads();
        // coalesced: 128 edges x 32 floats = 1024 float4, 256 threads x 4
#pragma unroll
        for (int r = 0; r < 4; r++) {
            int g = r * 256 + tid;
            int eloc = g >> 3, j = g & 7;
            obase[pass * 1024 + g] = *(const float4*)&buf[eloc * 36 + j * 4];
        }
        if (pass == 0) __syncthreads();
    }

    // ---- scatter record at the end (atomic + scattered store fire-and-forget) ----
    int p = atomicAdd(&cursor[se], 1);
    float4* op = (float4*)(sedge + (size_t)p * 8);
    op[0] = make_float4(dis, pre[0] * cjd, pre[1] * cjd, pre[2] * cjd);
    op[1] = make_float4(pre[3] * cjd, pre[4] * cjd, pre[5] * cjd, 0.f);
}

// ---------------- D: per-node aggregation, 8 edges (16 float4) in flight ---------
__global__ __launch_bounds__(256) void k_agg(const float* __restrict__ sedge,
                                             const int* __restrict__ offs,
                                             const int* __restrict__ cnt,
                                             float* __restrict__ msg_in) {
    int lane = threadIdx.x & 63;
    int n = blockIdx.x * 4 + (threadIdx.x >> 6);
    if (n >= N_NODES) return;
    int b = lane >> 1, th = lane & 1;
    float offb = (float)((double)b * STEP_D);
    int beg = offs[n];
    int deg = cnt[n];
    const float4* sp = (const float4*)sedge + (size_t)beg * 2;
    float a0 = 0.f, a1 = 0.f, a2 = 0.f;
    int i = 0;
    for (; i + 8 <= deg; i += 8) {
        float4 r[16];
#pragma unroll
        for (int u = 0; u < 16; u++) r[u] = sp[u];
        sp += 16;
#pragma unroll
        for (int u = 0; u < 8; u++) {
            float4 r0 = r[2 * u], r1 = r[2 * u + 1];
            float dd = r0.x - offb;
            float g = __expf(COEFF * dd * dd);
            float w0 = th ? r1.x : r0.y;
            float w1 = th ? r1.y : r0.z;
            float w2 = th ? r1.z : r0.w;
            a0 = fmaf(g, w0, a0);
            a1 = fmaf(g, w1, a1);
            a2 = fmaf(g, w2, a2);
        }
    }
    for (; i < deg; i++) {
        float4 r0 = sp[0], r1 = sp[1];
        sp += 2;
        float dd = r0.x - offb;
        float g = __expf(COEFF * dd * dd);
        float w0 = th ? r1.x : r0.y;
        float w1 = th ? r1.y : r0.z;
        float w2 = th ? r1.z : r0.w;
        a0 = fmaf(g, w0, a0);
        a1 = fmaf(g, w1, a1);
        a2 = fmaf(g, w2, a2);
    }
    float s = a0 * a0 + a1 * a1 + a2 * a2;
    float f2 = s + __shfl_xor(s, 1, 64);  // sum over all 6 t
    float p = f2 + 1e-9f;
    p = p * p;
    float tot = p;
#pragma unroll
    for (int m = 1; m < 64; m <<= 1) tot += __shfl_xor(tot, m, 64);
    // each b counted twice (both th lanes) -> halve
    float nrm = sqrtf(0.5f * tot);
    float val = f2 * fast_rcp(nrm + 1.0f);
    if (th == 0) msg_in[(size_t)n * NB + b] = val;
}

// ---------------- E: msg MLP (64 nodes/block, thread = 4 j x 8 nodes) ------------
__global__ __launch_bounds__(256) void k_msg(const float* __restrict__ msg_in,
                                             const float* __restrict__ w1,   // [32,128]
                                             const float* __restrict__ b1,
                                             const float* __restrict__ w2,   // [128,128]
                                             const float* __restrict__ b2,
                                             float* __restrict__ out) {
    __shared__ float mi[64 * 32];     // 8 KB input tile
    __shared__ float sh[64 * 128];    // 32 KB hidden tile
    int tid = threadIdx.x;
    int jq  = tid & 31;
    int ng  = tid >> 5;
    int j0  = jq * 4;
    int n0  = blockIdx.x * 64;

    // stage msg_in tile (64 nodes x 32 basis = 2048 floats)
    {
        const float4* srcp = (const float4*)msg_in;
        int base = n0 * 8;
        int maxi = N_NODES * 8 - 1;
#pragma unroll
        for (int r = 0; r < 2; r++) {
            int idx = base + r * 256 + tid;
            ((float4*)mi)[r * 256 + tid] = srcp[min(idx, maxi)];
        }
    }
    __syncthreads();

    float4 b1v = *(const float4*)&b1[j0];
    float h[8][4];
#pragma unroll
    for (int i = 0; i < 8; i++) {
        h[i][0] = b1v.x; h[i][1] = b1v.y; h[i][2] = b1v.z; h[i][3] = b1v.w;
    }
#pragma unroll
    for (int bb = 0; bb < 32; bb += 4) {
        float4 wv[4];
#pragma unroll
        for (int u = 0; u < 4; u++) wv[u] = *(const float4*)&w1[(bb + u) * 128 + j0];
#pragma unroll
        for (int i = 0; i < 8; i++) {
            float4 m4 = *(const float4*)&mi[(ng * 8 + i) * 32 + bb];
            h[i][0] = fmaf(m4.x, wv[0].x, h[i][0]);
            h[i][1] = fmaf(m4.x, wv[0].y, h[i][1]);
            h[i][2] = fmaf(m4.x, wv[0].z, h[i][2]);
            h[i][3] = fmaf(m4.x, wv[0].w, h[i][3]);
            h[i][0] = fmaf(m4.y, wv[1].x, h[i][0]);
            h[i][1] = fmaf(m4.y, wv[1].y, h[i][1]);
            h[i][2] = fmaf(m4.y, wv[1].z, h[i][2]);
            h[i][3] = fmaf(m4.y, wv[1].w, h[i][3]);
            h[i][0] = fmaf(m4.z, wv[2].x, h[i][0]);
            h[i][1] = fmaf(m4.z, wv[2].y, h[i][1]);
            h[i][2] = fmaf(m4.z, wv[2].z, h[i][2]);
            h[i][3] = fmaf(m4.z, wv[2].w, h[i][3]);
            h[i][0] = fmaf(m4.w, wv[3].x, h[i][0]);
            h[i][1] = fmaf(m4.w, wv[3].y, h[i][1]);
            h[i][2] = fmaf(m4.w, wv[3].z, h[i][2]);
            h[i][3] = fmaf(m4.w, wv[3].w, h[i][3]);
        }
    }
#pragma unroll
    for (int i = 0; i < 8; i++) {
        float4 sv = make_float4(silu_f(h[i][0]), silu_f(h[i][1]),
                                silu_f(h[i][2]), silu_f(h[i][3]));
        *(float4*)&sh[(ng * 8 + i) * 128 + j0] = sv;
    }
    __syncthreads();

    float4 b2v = *(const float4*)&b2[j0];
    float acc[8][4];
#pragma unroll
    for (int i = 0; i < 8; i++) {
        acc[i][0] = b2v.x; acc[i][1] = b2v.y; acc[i][2] = b2v.z; acc[i][3] = b2v.w;
    }
    for (int hb = 0; hb < 128; hb += 4) {
        float4 wv[4];
#pragma unroll
        for (int u = 0; u < 4; u++) wv[u] = *(const float4*)&w2[(hb + u) * 128 + j0];
#pragma unroll
        for (int i = 0; i < 8; i++) {
            float4 s4 = *(const float4*)&sh[(ng * 8 + i) * 128 + hb];
            acc[i][0] = fmaf(s4.x, wv[0].x, acc[i][0]);
            acc[i][1] = fmaf(s4.x, wv[0].y, acc[i][1]);
            acc[i][2] = fmaf(s4.x, wv[0].z, acc[i][2]);
            acc[i][3] = fmaf(s4.x, wv[0].w, acc[i][3]);
            acc[i][0] = fmaf(s4.y, wv[1].x, acc[i][0]);
            acc[i][1] = fmaf(s4.y, wv[1].y, acc[i][1]);
            acc[i][2] = fmaf(s4.y, wv[1].z, acc[i][2]);
            acc[i][3] = fmaf(s4.y, wv[1].w, acc[i][3]);
            acc[i][0] = fmaf(s4.z, wv[2].x, acc[i][0]);
            acc[i][1] = fmaf(s4.z, wv[2].y, acc[i][1]);
            acc[i][2] = fmaf(s4.z, wv[2].z, acc[i][2]);
            acc[i][3] = fmaf(s4.z, wv[2].w, acc[i][3]);
            acc[i][0] = fmaf(s4.w, wv[3].x, acc[i][0]);
            acc[i][1] = fmaf(s4.w, wv[3].y, acc[i][1]);
            acc[i][2] = fmaf(s4.w, wv[3].z, acc[i][2]);
            acc[i][3] = fmaf(s4.w, wv[3].w, acc[i][3]);
        }
    }
#pragma unroll
    for (int i = 0; i < 8; i++) {
        int n = n0 + ng * 8 + i;
        if (n < N_NODES) {
            *(float4*)&out[(size_t)n * 128 + j0] =
                make_float4(acc[i][0], acc[i][1], acc[i][2], acc[i][3]);
        }
    }
}

extern "C" void kernel_launch(void* const* d_in, const int* in_sizes, int n_in,
                              void* d_out, int out_size, void* d_ws, size_t ws_size,
                              hipStream_t stream) {
    (void)in_sizes; (void)n_in; (void)out_size; (void)ws_size;
    const float* feat    = (const float*)d_in[0];
    const float* dis_vec = (const float*)d_in[1];
    const float* cj_w1   = (const float*)d_in[2];
    const float* cj_b1   = (const float*)d_in[3];
    const float* cj_w2   = (const float*)d_in[4];
    const float* cj_b2   = (const float*)d_in[5];
    const float* msg_w1  = (const float*)d_in[6];
    const float* msg_b1  = (const float*)d_in[7];
    const float* msg_w2  = (const float*)d_in[8];
    const float* msg_b2  = (const float*)d_in[9];
    const float* filt_w1 = (const float*)d_in[10];
    const float* filt_w2 = (const float*)d_in[11];
    const float* filt_b2 = (const float*)d_in[12];
    const int*   src     = (const int*)d_in[13];
    const int*   dst     = (const int*)d_in[14];
    float* out = (float*)d_out;

    // workspace layout (elements), all 16B aligned; cnt+bsum zeroed in one memset
    float* ws     = (float*)d_ws;
    float* cj     = ws;                        // 50048 floats
    int*   cnt    = (int*)(cj + 50048);        // 50048 ints (zeroed)
    int*   bsum   = cnt + 50048;               // 64 ints   (zeroed)
    int*   offs   = bsum + 64;                 // 50048 ints
    int*   cursor = offs + 50048;              // 50048 ints
    float* msg_in = (float*)(cursor + 50048);  // 1600256 floats
    float* sedge  = msg_in + 1600256;          // 6400000 floats (25.6 MB)

    hipMemsetAsync(cnt, 0, (50048 + 64) * sizeof(int), stream);

    k_cj_count<<<CJ_BLOCKS + CNT_BLOCKS4, 256, 0, stream>>>(feat, cj_w1, cj_b1, cj_w2,
                                                            cj_b2, cj, src, cnt);
    k_scan<<<SCAN_BLOCKS, 1024, 0, stream>>>(cnt, offs, cursor, bsum);
    k_edge<<<EDGE_BLOCKS, 256, 0, stream>>>(src, dst, dis_vec, cj, cursor, sedge,
                                            filt_w1, filt_w2, filt_b2,
                                            out + (size_t)N_NODES * NA);
    k_agg<<<(N_NODES + 3) / 4, 256, 0, stream>>>(sedge, offs, cnt, msg_in);
    k_msg<<<(N_NODES + 63) / 64, 256, 0, stream>>>(msg_in, msg_w1, msg_b1, msg_w2, msg_b2, out);
}

// Round 11
// 345.060 us; speedup vs baseline: 1.0841x; 1.0300x over previous
//
#include <hip/hip_runtime.h>
#include <math.h>

#define N_NODES 50000
#define N_EDGES 800000
#define NB 32
#define NA 128
#define CJ_BLOCKS 782           // (N_NODES+63)/64
#define CNT_BLOCKS 3125         // N_EDGES/256 exactly
#define EDGE_BLOCKS 3125        // N_EDGES/256 exactly
#define SCAN_BLOCKS 49          // ceil(N_NODES/1024)

constexpr double STEP_D = 10.0 / 31.0;
constexpr float  STEP_F = (float)(10.0 / 31.0);       // matches np.float32 width
constexpr float  COEFF  = -0.5f / (STEP_F * STEP_F);  // -0.5/width^2
constexpr float  R2     = 1.41421356237309515f;       // sqrt(2) = PREF2 for mixed terms
constexpr float  INV_STEP = 3.1f;                     // 31/10
constexpr float  HWIN   = 2.05f;                      // g(HWIN) ~ 1.7e-9

__device__ __forceinline__ float fast_rcp(float x) {
    return __builtin_amdgcn_rcpf(x);   // v_rcp_f32, ~1ulp
}

__device__ __forceinline__ float silu_f(float x) {
    return x * fast_rcp(1.0f + __expf(-x));
}

// ---------------- A: fused cj-MLP (blocks < CJ_BLOCKS) + edge count (rest) --------
// count part stays scalar: its index loads are fully hidden under cj's FMA phase
// (R10 showed shrinking hidden work buys nothing).
__global__ __launch_bounds__(256) void k_cj_count(const float* __restrict__ feat,
                                                  const float* __restrict__ w1,
                                                  const float* __restrict__ b1,
                                                  const float* __restrict__ w2,
                                                  const float* __restrict__ b2,
                                                  float* __restrict__ cj,
                                                  const int* __restrict__ src,
                                                  int* __restrict__ cnt) {
    __shared__ float fls[64 * 128];   // 32 KB feat tile (unused by count blocks)
    int tid = threadIdx.x;
    int blk = blockIdx.x;
    if (blk >= CJ_BLOCKS) {
        int e = (blk - CJ_BLOCKS) * 256 + tid;
        if (e < N_EDGES) atomicAdd(&cnt[src[e]], 1);
        return;
    }
    int jq  = tid & 31;          // j quad: j0 = 4*jq
    int ng  = tid >> 5;          // node group 0..7 (8 nodes each)
    int j0  = jq * 4;
    int n0  = blk * 64;

    // stage feat tile (coalesced float4, clamped for tail block)
    {
        const float4* fp = (const float4*)feat;
        int base = n0 * 32;                    // float4 index
        int maxi = N_NODES * 32 - 1;
#pragma unroll
        for (int r = 0; r < 8; r++) {
            int idx = base + r * 256 + tid;
            ((float4*)fls)[r * 256 + tid] = fp[min(idx, maxi)];
        }
    }
    __syncthreads();

    float4 bv = *(const float4*)&b1[j0];
    float h[8][4];
#pragma unroll
    for (int i = 0; i < 8; i++) {
        h[i][0] = bv.x; h[i][1] = bv.y; h[i][2] = bv.z; h[i][3] = bv.w;
    }
    for (int kb = 0; kb < 128; kb += 4) {
        float4 wv[4];
#pragma unroll
        for (int u = 0; u < 4; u++) wv[u] = *(const float4*)&w1[(kb + u) * 128 + j0];
#pragma unroll
        for (int i = 0; i < 8; i++) {
            float4 f4 = *(const float4*)&fls[(ng * 8 + i) * 128 + kb];
            h[i][0] = fmaf(f4.x, wv[0].x, h[i][0]);
            h[i][1] = fmaf(f4.x, wv[0].y, h[i][1]);
            h[i][2] = fmaf(f4.x, wv[0].z, h[i][2]);
            h[i][3] = fmaf(f4.x, wv[0].w, h[i][3]);
            h[i][0] = fmaf(f4.y, wv[1].x, h[i][0]);
            h[i][1] = fmaf(f4.y, wv[1].y, h[i][1]);
            h[i][2] = fmaf(f4.y, wv[1].z, h[i][2]);
            h[i][3] = fmaf(f4.y, wv[1].w, h[i][3]);
            h[i][0] = fmaf(f4.z, wv[2].x, h[i][0]);
            h[i][1] = fmaf(f4.z, wv[2].y, h[i][1]);
            h[i][2] = fmaf(f4.z, wv[2].z, h[i][2]);
            h[i][3] = fmaf(f4.z, wv[2].w, h[i][3]);
            h[i][0] = fmaf(f4.w, wv[3].x, h[i][0]);
            h[i][1] = fmaf(f4.w, wv[3].y, h[i][1]);
            h[i][2] = fmaf(f4.w, wv[3].z, h[i][2]);
            h[i][3] = fmaf(f4.w, wv[3].w, h[i][3]);
        }
    }
    // epilogue: cj[n] = b2 + sum_j silu(h)*w2[j]; reduce across the 32-lane jq group
    float4 w2v = *(const float4*)&w2[j0];
    float keep = 0.f;
#pragma unroll
    for (int i = 0; i < 8; i++) {
        float v = silu_f(h[i][0]) * w2v.x + silu_f(h[i][1]) * w2v.y
                + silu_f(h[i][2]) * w2v.z + silu_f(h[i][3]) * w2v.w;
#pragma unroll
        for (int m = 1; m < 32; m <<= 1) v += __shfl_xor(v, m, 64);
        if (jq == i) keep = v;
    }
    if (jq < 8) {
        int n = n0 + ng * 8 + jq;
        if (n < N_NODES) cj[n] = b2[0] + keep;
    }
}

// ---------------- B: single-kernel scan (49 co-resident blocks, flag sync) -------
__global__ __launch_bounds__(1024) void k_scan(const int* __restrict__ cnt,
                                               int* __restrict__ offs,
                                               int* __restrict__ cursor,
                                               int* __restrict__ bsum) {
    __shared__ int s[1024];
    __shared__ int sbase;
    int bid = blockIdx.x;
    int i = bid * 1024 + threadIdx.x;
    int v = (i < N_NODES) ? cnt[i] : 0;
    s[threadIdx.x] = v;
    __syncthreads();
    for (int o = 1; o < 1024; o <<= 1) {
        int t = (threadIdx.x >= (unsigned)o) ? s[threadIdx.x - o] : 0;
        __syncthreads();
        s[threadIdx.x] += t;
        __syncthreads();
    }
    if (threadIdx.x == 1023) atomicExch(&bsum[bid], s[1023] + 1);  // flag: nonzero
    if (threadIdx.x < 64) {
        int lane = threadIdx.x;
        int val = 0;
        if (lane < bid) {
            int t;
            do { t = atomicAdd(&bsum[lane], 0); } while (t == 0);
            val = t - 1;
        }
#pragma unroll
        for (int m = 1; m < 64; m <<= 1) val += __shfl_xor(val, m, 64);
        if (lane == 0) sbase = val;
    }
    __syncthreads();
    if (i < N_NODES) {
        int o2 = s[threadIdx.x] - v + sbase;   // exclusive-in-block + block base
        offs[i] = o2;
        cursor[i] = o2;
    }
}

// ---------------- C: fused edge pass, thread-per-edge, two-pass LDS stage --------
__global__ __launch_bounds__(256) void k_edge(const int* __restrict__ src,
                                              const int* __restrict__ dst,
                                              const float* __restrict__ dis_vec,
                                              const float* __restrict__ cj,
                                              int* __restrict__ cursor,
                                              float* __restrict__ sedge,
                                              const float* __restrict__ fw1,
                                              const float* __restrict__ fw2,
                                              const float* __restrict__ fb2,
                                              float* __restrict__ outf) {
    __shared__ float buf[128 * 36];   // 18 KB
    int tid = threadIdx.x;
    int e = blockIdx.x * 256 + tid;   // grid exact: e < N_EDGES always
    // issue graph-index loads early; consumed only at the end
    int se = src[e];
    int de = dst[e];
    float cjd = cj[de];

    float dx = dis_vec[3 * e], dy = dis_vec[3 * e + 1], dz = dis_vec[3 * e + 2];
    float ax = dx + 1e-9f, ay = dy + 1e-9f, az = dz + 1e-9f;
    float dis = sqrtf(ax * ax + ay * ay + az * az);
    float x = dx + 1e-8f, y = dy + 1e-8f, z = dz + 1e-8f;
    // prefactor * PREF2, t order: (0,0,2),(0,1,1),(0,2,0),(1,0,1),(1,1,0),(2,0,0)
    float pre[6];
    pre[0] = z * z;      pre[1] = y * z * R2; pre[2] = y * y;
    pre[3] = x * z * R2; pre[4] = x * y * R2; pre[5] = x * x;

    float A = 0.f, B = 0.f;
#pragma unroll
    for (int t = 0; t < 6; t++) { A = fmaf(pre[t], pre[t], A); B += pre[t]; }
    float q[6];
#pragma unroll
    for (int tp = 0; tp < 6; tp++) {
        float s = 0.f;
#pragma unroll
        for (int t = 0; t < 6; t++) s = fmaf(pre[t], fw1[t * 6 + tp], s);
        q[tp] = s;
    }
    float bias = fb2[0];
    float w2r[6];
#pragma unroll
    for (int t = 0; t < 6; t++) w2r[t] = fw2[t];

    int b_lo = (int)ceilf((dis - HWIN) * INV_STEP);

    // window values into registers (all static indices -> stays in VGPRs)
    float os[14];
#pragma unroll
    for (int k = 0; k < 14; k++) {
        float offb = (float)((double)(b_lo + k) * STEP_D);
        float dd = dis - offb;
        float g = __expf(COEFF * dd * dd);
        float ns = fmaf(g * g, A, fmaf(2e-8f * g, B, 6e-16f));
        float rn = fast_rcp(sqrtf(ns) + 1.0f);
        float sg = g * rn;
        float o = bias;
#pragma unroll
        for (int tp = 0; tp < 6; tp++) o = fmaf(silu_f(sg * q[tp]), w2r[tp], o);
        os[k] = o;
    }

    int half = tid >> 7;        // wave-uniform: waves 0-1 -> 0, waves 2-3 -> 1
    int lrow = tid & 127;
    float4* obase = (float4*)outf + (size_t)blockIdx.x * 2048;
#pragma unroll
    for (int pass = 0; pass < 2; pass++) {
        if (half == pass) {
            float* row = &buf[lrow * 36];
            float4 b4v = make_float4(bias, bias, bias, bias);
#pragma unroll
            for (int r = 0; r < 8; r++) ((float4*)row)[r] = b4v;
#pragma unroll
            for (int k = 0; k < 14; k++) {
                int b = b_lo + k;
                if ((unsigned)b < 32u) row[b] = os[k];
            }
        }
        __syncthreads();
        // coalesced: 128 edges x 32 floats = 1024 float4, 256 threads x 4
#pragma unroll
        for (int r = 0; r < 4; r++) {
            int g = r * 256 + tid;
            int eloc = g >> 3, j = g & 7;
            obase[pass * 1024 + g] = *(const float4*)&buf[eloc * 36 + j * 4];
        }
        if (pass == 0) __syncthreads();
    }

    // ---- scatter record at the end (atomic + scattered store fire-and-forget) ----
    int p = atomicAdd(&cursor[se], 1);
    float4* op = (float4*)(sedge + (size_t)p * 8);
    op[0] = make_float4(dis, pre[0] * cjd, pre[1] * cjd, pre[2] * cjd);
    op[1] = make_float4(pre[3] * cjd, pre[4] * cjd, pre[5] * cjd, 0.f);
}

// ---------------- D: per-node aggregation, 8 edges (16 float4) in flight ---------
__global__ __launch_bounds__(256) void k_agg(const float* __restrict__ sedge,
                                             const int* __restrict__ offs,
                                             const int* __restrict__ cnt,
                                             float* __restrict__ msg_in) {
    int lane = threadIdx.x & 63;
    int n = blockIdx.x * 4 + (threadIdx.x >> 6);
    if (n >= N_NODES) return;
    int b = lane >> 1, th = lane & 1;
    float offb = (float)((double)b * STEP_D);
    int beg = offs[n];
    int deg = cnt[n];
    const float4* sp = (const float4*)sedge + (size_t)beg * 2;
    float a0 = 0.f, a1 = 0.f, a2 = 0.f;
    int i = 0;
    for (; i + 8 <= deg; i += 8) {
        float4 r[16];
#pragma unroll
        for (int u = 0; u < 16; u++) r[u] = sp[u];
        sp += 16;
#pragma unroll
        for (int u = 0; u < 8; u++) {
            float4 r0 = r[2 * u], r1 = r[2 * u + 1];
            float dd = r0.x - offb;
            float g = __expf(COEFF * dd * dd);
            float w0 = th ? r1.x : r0.y;
            float w1 = th ? r1.y : r0.z;
            float w2 = th ? r1.z : r0.w;
            a0 = fmaf(g, w0, a0);
            a1 = fmaf(g, w1, a1);
            a2 = fmaf(g, w2, a2);
        }
    }
    for (; i < deg; i++) {
        float4 r0 = sp[0], r1 = sp[1];
        sp += 2;
        float dd = r0.x - offb;
        float g = __expf(COEFF * dd * dd);
        float w0 = th ? r1.x : r0.y;
        float w1 = th ? r1.y : r0.z;
        float w2 = th ? r1.z : r0.w;
        a0 = fmaf(g, w0, a0);
        a1 = fmaf(g, w1, a1);
        a2 = fmaf(g, w2, a2);
    }
    float s = a0 * a0 + a1 * a1 + a2 * a2;
    float f2 = s + __shfl_xor(s, 1, 64);  // sum over all 6 t
    float p = f2 + 1e-9f;
    p = p * p;
    float tot = p;
#pragma unroll
    for (int m = 1; m < 64; m <<= 1) tot += __shfl_xor(tot, m, 64);
    // each b counted twice (both th lanes) -> halve
    float nrm = sqrtf(0.5f * tot);
    float val = f2 * fast_rcp(nrm + 1.0f);
    if (th == 0) msg_in[(size_t)n * NB + b] = val;
}

// ---------------- E: msg MLP (64 nodes/block, thread = 4 j x 8 nodes) ------------
__global__ __launch_bounds__(256) void k_msg(const float* __restrict__ msg_in,
                                             const float* __restrict__ w1,   // [32,128]
                                             const float* __restrict__ b1,
                                             const float* __restrict__ w2,   // [128,128]
                                             const float* __restrict__ b2,
                                             float* __restrict__ out) {
    __shared__ float mi[64 * 32];     // 8 KB input tile
    __shared__ float sh[64 * 128];    // 32 KB hidden tile
    int tid = threadIdx.x;
    int jq  = tid & 31;
    int ng  = tid >> 5;
    int j0  = jq * 4;
    int n0  = blockIdx.x * 64;

    // stage msg_in tile (64 nodes x 32 basis = 2048 floats)
    {
        const float4* srcp = (const float4*)msg_in;
        int base = n0 * 8;
        int maxi = N_NODES * 8 - 1;
#pragma unroll
        for (int r = 0; r < 2; r++) {
            int idx = base + r * 256 + tid;
            ((float4*)mi)[r * 256 + tid] = srcp[min(idx, maxi)];
        }
    }
    __syncthreads();

    float4 b1v = *(const float4*)&b1[j0];
    float h[8][4];
#pragma unroll
    for (int i = 0; i < 8; i++) {
        h[i][0] = b1v.x; h[i][1] = b1v.y; h[i][2] = b1v.z; h[i][3] = b1v.w;
    }
#pragma unroll
    for (int bb = 0; bb < 32; bb += 4) {
        float4 wv[4];
#pragma unroll
        for (int u = 0; u < 4; u++) wv[u] = *(const float4*)&w1[(bb + u) * 128 + j0];
#pragma unroll
        for (int i = 0; i < 8; i++) {
            float4 m4 = *(const float4*)&mi[(ng * 8 + i) * 32 + bb];
            h[i][0] = fmaf(m4.x, wv[0].x, h[i][0]);
            h[i][1] = fmaf(m4.x, wv[0].y, h[i][1]);
            h[i][2] = fmaf(m4.x, wv[0].z, h[i][2]);
            h[i][3] = fmaf(m4.x, wv[0].w, h[i][3]);
            h[i][0] = fmaf(m4.y, wv[1].x, h[i][0]);
            h[i][1] = fmaf(m4.y, wv[1].y, h[i][1]);
            h[i][2] = fmaf(m4.y, wv[1].z, h[i][2]);
            h[i][3] = fmaf(m4.y, wv[1].w, h[i][3]);
            h[i][0] = fmaf(m4.z, wv[2].x, h[i][0]);
            h[i][1] = fmaf(m4.z, wv[2].y, h[i][1]);
            h[i][2] = fmaf(m4.z, wv[2].z, h[i][2]);
            h[i][3] = fmaf(m4.z, wv[2].w, h[i][3]);
            h[i][0] = fmaf(m4.w, wv[3].x, h[i][0]);
            h[i][1] = fmaf(m4.w, wv[3].y, h[i][1]);
            h[i][2] = fmaf(m4.w, wv[3].z, h[i][2]);
            h[i][3] = fmaf(m4.w, wv[3].w, h[i][3]);
        }
    }
#pragma unroll
    for (int i = 0; i < 8; i++) {
        float4 sv = make_float4(silu_f(h[i][0]), silu_f(h[i][1]),
                                silu_f(h[i][2]), silu_f(h[i][3]));
        *(float4*)&sh[(ng * 8 + i) * 128 + j0] = sv;
    }
    __syncthreads();

    float4 b2v = *(const float4*)&b2[j0];
    float acc[8][4];
#pragma unroll
    for (int i = 0; i < 8; i++) {
        acc[i][0] = b2v.x; acc[i][1] = b2v.y; acc[i][2] = b2v.z; acc[i][3] = b2v.w;
    }
    for (int hb = 0; hb < 128; hb += 4) {
        float4 wv[4];
#pragma unroll
        for (int u = 0; u < 4; u++) wv[u] = *(const float4*)&w2[(hb + u) * 128 + j0];
#pragma unroll
        for (int i = 0; i < 8; i++) {
            float4 s4 = *(const float4*)&sh[(ng * 8 + i) * 128 + hb];
            acc[i][0] = fmaf(s4.x, wv[0].x, acc[i][0]);
            acc[i][1] = fmaf(s4.x, wv[0].y, acc[i][1]);
            acc[i][2] = fmaf(s4.x, wv[0].z, acc[i][2]);
            acc[i][3] = fmaf(s4.x, wv[0].w, acc[i][3]);
            acc[i][0] = fmaf(s4.y, wv[1].x, acc[i][0]);
            acc[i][1] = fmaf(s4.y, wv[1].y, acc[i][1]);
            acc[i][2] = fmaf(s4.y, wv[1].z, acc[i][2]);
            acc[i][3] = fmaf(s4.y, wv[1].w, acc[i][3]);
            acc[i][0] = fmaf(s4.z, wv[2].x, acc[i][0]);
            acc[i][1] = fmaf(s4.z, wv[2].y, acc[i][1]);
            acc[i][2] = fmaf(s4.z, wv[2].z, acc[i][2]);
            acc[i][3] = fmaf(s4.z, wv[2].w, acc[i][3]);
            acc[i][0] = fmaf(s4.w, wv[3].x, acc[i][0]);
            acc[i][1] = fmaf(s4.w, wv[3].y, acc[i][1]);
            acc[i][2] = fmaf(s4.w, wv[3].z, acc[i][2]);
            acc[i][3] = fmaf(s4.w, wv[3].w, acc[i][3]);
        }
    }
#pragma unroll
    for (int i = 0; i < 8; i++) {
        int n = n0 + ng * 8 + i;
        if (n < N_NODES) {
            *(float4*)&out[(size_t)n * 128 + j0] =
                make_float4(acc[i][0], acc[i][1], acc[i][2], acc[i][3]);
        }
    }
}

extern "C" void kernel_launch(void* const* d_in, const int* in_sizes, int n_in,
                              void* d_out, int out_size, void* d_ws, size_t ws_size,
                              hipStream_t stream) {
    (void)in_sizes; (void)n_in; (void)out_size; (void)ws_size;
    const float* feat    = (const float*)d_in[0];
    const float* dis_vec = (const float*)d_in[1];
    const float* cj_w1   = (const float*)d_in[2];
    const float* cj_b1   = (const float*)d_in[3];
    const float* cj_w2   = (const float*)d_in[4];
    const float* cj_b2   = (const float*)d_in[5];
    const float* msg_w1  = (const float*)d_in[6];
    const float* msg_b1  = (const float*)d_in[7];
    const float* msg_w2  = (const float*)d_in[8];
    const float* msg_b2  = (const float*)d_in[9];
    const float* filt_w1 = (const float*)d_in[10];
    const float* filt_w2 = (const float*)d_in[11];
    const float* filt_b2 = (const float*)d_in[12];
    const int*   src     = (const int*)d_in[13];
    const int*   dst     = (const int*)d_in[14];
    float* out = (float*)d_out;

    // workspace layout (elements), all 16B aligned; cnt+bsum zeroed in one memset
    float* ws     = (float*)d_ws;
    float* cj     = ws;                        // 50048 floats
    int*   cnt    = (int*)(cj + 50048);        // 50048 ints (zeroed)
    int*   bsum   = cnt + 50048;               // 64 ints   (zeroed)
    int*   offs   = bsum + 64;                 // 50048 ints
    int*   cursor = offs + 50048;              // 50048 ints
    float* msg_in = (float*)(cursor + 50048);  // 1600256 floats
    float* sedge  = msg_in + 1600256;          // 6400000 floats (25.6 MB)

    hipMemsetAsync(cnt, 0, (50048 + 64) * sizeof(int), stream);

    k_cj_count<<<CJ_BLOCKS + CNT_BLOCKS, 256, 0, stream>>>(feat, cj_w1, cj_b1, cj_w2,
                                                           cj_b2, cj, src, cnt);
    k_scan<<<SCAN_BLOCKS, 1024, 0, stream>>>(cnt, offs, cursor, bsum);
    k_edge<<<EDGE_BLOCKS, 256, 0, stream>>>(src, dst, dis_vec, cj, cursor, sedge,
                                            filt_w1, filt_w2, filt_b2,
                                            out + (size_t)N_NODES * NA);
    k_agg<<<(N_NODES + 3) / 4, 256, 0, stream>>>(sedge, offs, cnt, msg_in);
    k_msg<<<(N_NODES + 63) / 64, 256, 0, stream>>>(msg_in, msg_w1, msg_b1, msg_w2, msg_b2, out);
}

// Round 12
// 341.862 us; speedup vs baseline: 1.0943x; 1.0094x over previous
//
#include <hip/hip_runtime.h>
#include <math.h>

#define N_NODES 50000
#define N_EDGES 800000
#define NB 32
#define NA 128
#define CJ_BLOCKS 782           // (N_NODES+63)/64
#define CNT_BLOCKS 3125         // N_EDGES/256 exactly
#define EDGE_BLOCKS 3125        // N_EDGES/256 exactly
#define SCAN_BLOCKS 49          // ceil(N_NODES/1024)

constexpr double STEP_D = 10.0 / 31.0;
constexpr float  STEP_F = (float)(10.0 / 31.0);       // matches np.float32 width
constexpr float  COEFF  = -0.5f / (STEP_F * STEP_F);  // -0.5/width^2
constexpr float  R2     = 1.41421356237309515f;       // sqrt(2) = PREF2 for mixed terms
constexpr float  INV_STEP = 3.1f;                     // 31/10
constexpr float  HWIN   = 2.05f;                      // g(HWIN) ~ 1.7e-9

__device__ __forceinline__ float fast_rcp(float x) {
    return __builtin_amdgcn_rcpf(x);   // v_rcp_f32, ~1ulp
}

__device__ __forceinline__ float silu_f(float x) {
    return x * fast_rcp(1.0f + __expf(-x));
}

// ---------------- A: fused cj-MLP (blocks < CJ_BLOCKS) + edge count (rest) --------
__global__ __launch_bounds__(256) void k_cj_count(const float* __restrict__ feat,
                                                  const float* __restrict__ w1,
                                                  const float* __restrict__ b1,
                                                  const float* __restrict__ w2,
                                                  const float* __restrict__ b2,
                                                  float* __restrict__ cj,
                                                  const int* __restrict__ src,
                                                  int* __restrict__ cnt) {
    __shared__ float fls[64 * 128];   // 32 KB feat tile (unused by count blocks)
    int tid = threadIdx.x;
    int blk = blockIdx.x;
    if (blk >= CJ_BLOCKS) {
        int e = (blk - CJ_BLOCKS) * 256 + tid;
        if (e < N_EDGES) atomicAdd(&cnt[src[e]], 1);
        return;
    }
    int jq  = tid & 31;          // j quad: j0 = 4*jq
    int ng  = tid >> 5;          // node group 0..7 (8 nodes each)
    int j0  = jq * 4;
    int n0  = blk * 64;

    // stage feat tile (coalesced float4, clamped for tail block)
    {
        const float4* fp = (const float4*)feat;
        int base = n0 * 32;                    // float4 index
        int maxi = N_NODES * 32 - 1;
#pragma unroll
        for (int r = 0; r < 8; r++) {
            int idx = base + r * 256 + tid;
            ((float4*)fls)[r * 256 + tid] = fp[min(idx, maxi)];
        }
    }
    __syncthreads();

    float4 bv = *(const float4*)&b1[j0];
    float h[8][4];
#pragma unroll
    for (int i = 0; i < 8; i++) {
        h[i][0] = bv.x; h[i][1] = bv.y; h[i][2] = bv.z; h[i][3] = bv.w;
    }
    for (int kb = 0; kb < 128; kb += 4) {
        float4 wv[4];
#pragma unroll
        for (int u = 0; u < 4; u++) wv[u] = *(const float4*)&w1[(kb + u) * 128 + j0];
#pragma unroll
        for (int i = 0; i < 8; i++) {
            float4 f4 = *(const float4*)&fls[(ng * 8 + i) * 128 + kb];
            h[i][0] = fmaf(f4.x, wv[0].x, h[i][0]);
            h[i][1] = fmaf(f4.x, wv[0].y, h[i][1]);
            h[i][2] = fmaf(f4.x, wv[0].z, h[i][2]);
            h[i][3] = fmaf(f4.x, wv[0].w, h[i][3]);
            h[i][0] = fmaf(f4.y, wv[1].x, h[i][0]);
            h[i][1] = fmaf(f4.y, wv[1].y, h[i][1]);
            h[i][2] = fmaf(f4.y, wv[1].z, h[i][2]);
            h[i][3] = fmaf(f4.y, wv[1].w, h[i][3]);
            h[i][0] = fmaf(f4.z, wv[2].x, h[i][0]);
            h[i][1] = fmaf(f4.z, wv[2].y, h[i][1]);
            h[i][2] = fmaf(f4.z, wv[2].z, h[i][2]);
            h[i][3] = fmaf(f4.z, wv[2].w, h[i][3]);
            h[i][0] = fmaf(f4.w, wv[3].x, h[i][0]);
            h[i][1] = fmaf(f4.w, wv[3].y, h[i][1]);
            h[i][2] = fmaf(f4.w, wv[3].z, h[i][2]);
            h[i][3] = fmaf(f4.w, wv[3].w, h[i][3]);
        }
    }
    // epilogue: cj[n] = b2 + sum_j silu(h)*w2[j]; reduce across the 32-lane jq group
    float4 w2v = *(const float4*)&w2[j0];
    float keep = 0.f;
#pragma unroll
    for (int i = 0; i < 8; i++) {
        float v = silu_f(h[i][0]) * w2v.x + silu_f(h[i][1]) * w2v.y
                + silu_f(h[i][2]) * w2v.z + silu_f(h[i][3]) * w2v.w;
#pragma unroll
        for (int m = 1; m < 32; m <<= 1) v += __shfl_xor(v, m, 64);
        if (jq == i) keep = v;
    }
    if (jq < 8) {
        int n = n0 + ng * 8 + jq;
        if (n < N_NODES) cj[n] = b2[0] + keep;
    }
}

// ---------------- B: single-kernel scan (49 co-resident blocks, flag sync) -------
__global__ __launch_bounds__(1024) void k_scan(const int* __restrict__ cnt,
                                               int* __restrict__ offs,
                                               int* __restrict__ cursor,
                                               int* __restrict__ bsum) {
    __shared__ int s[1024];
    __shared__ int sbase;
    int bid = blockIdx.x;
    int i = bid * 1024 + threadIdx.x;
    int v = (i < N_NODES) ? cnt[i] : 0;
    s[threadIdx.x] = v;
    __syncthreads();
    for (int o = 1; o < 1024; o <<= 1) {
        int t = (threadIdx.x >= (unsigned)o) ? s[threadIdx.x - o] : 0;
        __syncthreads();
        s[threadIdx.x] += t;
        __syncthreads();
    }
    if (threadIdx.x == 1023) atomicExch(&bsum[bid], s[1023] + 1);  // flag: nonzero
    if (threadIdx.x < 64) {
        int lane = threadIdx.x;
        int val = 0;
        if (lane < bid) {
            int t;
            do { t = atomicAdd(&bsum[lane], 0); } while (t == 0);
            val = t - 1;
        }
#pragma unroll
        for (int m = 1; m < 64; m <<= 1) val += __shfl_xor(val, m, 64);
        if (lane == 0) sbase = val;
    }
    __syncthreads();
    if (i < N_NODES) {
        int o2 = s[threadIdx.x] - v + sbase;   // exclusive-in-block + block base
        offs[i] = o2;
        cursor[i] = o2;
    }
}

// ---------------- C: fused edge pass, thread-per-edge, two-pass LDS stage --------
// sedge record compressed to ONE float4 (x, y, z, cjd) = 16 B/edge: halves the
// scattered-store bytes + RFO overhead; k_agg recomputes pre/dis (cheap, latency-
// bound loop has VALU headroom).
__global__ __launch_bounds__(256) void k_edge(const int* __restrict__ src,
                                              const int* __restrict__ dst,
                                              const float* __restrict__ dis_vec,
                                              const float* __restrict__ cj,
                                              int* __restrict__ cursor,
                                              float* __restrict__ sedge,
                                              const float* __restrict__ fw1,
                                              const float* __restrict__ fw2,
                                              const float* __restrict__ fb2,
                                              float* __restrict__ outf) {
    __shared__ float buf[128 * 36];   // 18 KB
    int tid = threadIdx.x;
    int e = blockIdx.x * 256 + tid;   // grid exact: e < N_EDGES always
    // issue graph-index loads early; consumed only at the end
    int se = src[e];
    int de = dst[e];
    float cjd = cj[de];

    float dx = dis_vec[3 * e], dy = dis_vec[3 * e + 1], dz = dis_vec[3 * e + 2];
    float ax = dx + 1e-9f, ay = dy + 1e-9f, az = dz + 1e-9f;
    float dis = sqrtf(ax * ax + ay * ay + az * az);
    float x = dx + 1e-8f, y = dy + 1e-8f, z = dz + 1e-8f;
    // prefactor * PREF2, t order: (0,0,2),(0,1,1),(0,2,0),(1,0,1),(1,1,0),(2,0,0)
    float pre[6];
    pre[0] = z * z;      pre[1] = y * z * R2; pre[2] = y * y;
    pre[3] = x * z * R2; pre[4] = x * y * R2; pre[5] = x * x;

    float A = 0.f, B = 0.f;
#pragma unroll
    for (int t = 0; t < 6; t++) { A = fmaf(pre[t], pre[t], A); B += pre[t]; }
    float q[6];
#pragma unroll
    for (int tp = 0; tp < 6; tp++) {
        float s = 0.f;
#pragma unroll
        for (int t = 0; t < 6; t++) s = fmaf(pre[t], fw1[t * 6 + tp], s);
        q[tp] = s;
    }
    float bias = fb2[0];
    float w2r[6];
#pragma unroll
    for (int t = 0; t < 6; t++) w2r[t] = fw2[t];

    int b_lo = (int)ceilf((dis - HWIN) * INV_STEP);

    // window values into registers (all static indices -> stays in VGPRs)
    float os[14];
#pragma unroll
    for (int k = 0; k < 14; k++) {
        float offb = (float)((double)(b_lo + k) * STEP_D);
        float dd = dis - offb;
        float g = __expf(COEFF * dd * dd);
        float ns = fmaf(g * g, A, fmaf(2e-8f * g, B, 6e-16f));
        float rn = fast_rcp(sqrtf(ns) + 1.0f);
        float sg = g * rn;
        float o = bias;
#pragma unroll
        for (int tp = 0; tp < 6; tp++) o = fmaf(silu_f(sg * q[tp]), w2r[tp], o);
        os[k] = o;
    }

    int half = tid >> 7;        // wave-uniform: waves 0-1 -> 0, waves 2-3 -> 1
    int lrow = tid & 127;
    float4* obase = (float4*)outf + (size_t)blockIdx.x * 2048;
#pragma unroll
    for (int pass = 0; pass < 2; pass++) {
        if (half == pass) {
            float* row = &buf[lrow * 36];
            float4 b4v = make_float4(bias, bias, bias, bias);
#pragma unroll
            for (int r = 0; r < 8; r++) ((float4*)row)[r] = b4v;
#pragma unroll
            for (int k = 0; k < 14; k++) {
                int b = b_lo + k;
                if ((unsigned)b < 32u) row[b] = os[k];
            }
        }
        __syncthreads();
        // coalesced: 128 edges x 32 floats = 1024 float4, 256 threads x 4
#pragma unroll
        for (int r = 0; r < 4; r++) {
            int g = r * 256 + tid;
            int eloc = g >> 3, j = g & 7;
            obase[pass * 1024 + g] = *(const float4*)&buf[eloc * 36 + j * 4];
        }
        if (pass == 0) __syncthreads();
    }

    // ---- scatter compressed record at the end (fire-and-forget) ----
    int p = atomicAdd(&cursor[se], 1);
    *(float4*)(sedge + (size_t)p * 4) = make_float4(x, y, z, cjd);
}

// ---------------- D: per-node aggregation, 8 edges (8 float4) in flight ----------
// Recomputes pre/dis from the 16B record. dis uses +1e-8 offsets (ref: +1e-9);
// |dg| ~ 6e-7, far inside tolerance. cjd folded into g.
__global__ __launch_bounds__(256) void k_agg(const float* __restrict__ sedge,
                                             const int* __restrict__ offs,
                                             const int* __restrict__ cnt,
                                             float* __restrict__ msg_in) {
    int lane = threadIdx.x & 63;
    int n = blockIdx.x * 4 + (threadIdx.x >> 6);
    if (n >= N_NODES) return;
    int b = lane >> 1, th = lane & 1;
    float offb = (float)((double)b * STEP_D);
    int beg = offs[n];
    int deg = cnt[n];
    const float4* sp = (const float4*)sedge + beg;
    float a0 = 0.f, a1 = 0.f, a2 = 0.f;
    int i = 0;
    for (; i + 8 <= deg; i += 8) {
        float4 r[8];
#pragma unroll
        for (int u = 0; u < 8; u++) r[u] = sp[u];
        sp += 8;
#pragma unroll
        for (int u = 0; u < 8; u++) {
            float x = r[u].x, y = r[u].y, z = r[u].z, cjd = r[u].w;
            float zz = z * z, yy = y * y, xx = x * x;
            float xr = x * R2, yr = y * R2;
            float dis = sqrtf(xx + yy + zz);
            float dd = dis - offb;
            float gc = __expf(COEFF * dd * dd) * cjd;
            float w0 = th ? xr * z : zz;
            float w1 = th ? xr * y : yr * z;
            float w2 = th ? xx     : yy;
            a0 = fmaf(gc, w0, a0);
            a1 = fmaf(gc, w1, a1);
            a2 = fmaf(gc, w2, a2);
        }
    }
    for (; i < deg; i++) {
        float4 r0 = sp[0];
        sp += 1;
        float x = r0.x, y = r0.y, z = r0.z, cjd = r0.w;
        float zz = z * z, yy = y * y, xx = x * x;
        float xr = x * R2, yr = y * R2;
        float dis = sqrtf(xx + yy + zz);
        float dd = dis - offb;
        float gc = __expf(COEFF * dd * dd) * cjd;
        float w0 = th ? xr * z : zz;
        float w1 = th ? xr * y : yr * z;
        float w2 = th ? xx     : yy;
        a0 = fmaf(gc, w0, a0);
        a1 = fmaf(gc, w1, a1);
        a2 = fmaf(gc, w2, a2);
    }
    float s = a0 * a0 + a1 * a1 + a2 * a2;
    float f2 = s + __shfl_xor(s, 1, 64);  // sum over all 6 t
    float p = f2 + 1e-9f;
    p = p * p;
    float tot = p;
#pragma unroll
    for (int m = 1; m < 64; m <<= 1) tot += __shfl_xor(tot, m, 64);
    // each b counted twice (both th lanes) -> halve
    float nrm = sqrtf(0.5f * tot);
    float val = f2 * fast_rcp(nrm + 1.0f);
    if (th == 0) msg_in[(size_t)n * NB + b] = val;
}

// ---------------- E: msg MLP (64 nodes/block, thread = 4 j x 8 nodes) ------------
__global__ __launch_bounds__(256) void k_msg(const float* __restrict__ msg_in,
                                             const float* __restrict__ w1,   // [32,128]
                                             const float* __restrict__ b1,
                                             const float* __restrict__ w2,   // [128,128]
                                             const float* __restrict__ b2,
                                             float* __restrict__ out) {
    __shared__ float mi[64 * 32];     // 8 KB input tile
    __shared__ float sh[64 * 128];    // 32 KB hidden tile
    int tid = threadIdx.x;
    int jq  = tid & 31;
    int ng  = tid >> 5;
    int j0  = jq * 4;
    int n0  = blockIdx.x * 64;

    // stage msg_in tile (64 nodes x 32 basis = 2048 floats)
    {
        const float4* srcp = (const float4*)msg_in;
        int base = n0 * 8;
        int maxi = N_NODES * 8 - 1;
#pragma unroll
        for (int r = 0; r < 2; r++) {
            int idx = base + r * 256 + tid;
            ((float4*)mi)[r * 256 + tid] = srcp[min(idx, maxi)];
        }
    }
    __syncthreads();

    float4 b1v = *(const float4*)&b1[j0];
    float h[8][4];
#pragma unroll
    for (int i = 0; i < 8; i++) {
        h[i][0] = b1v.x; h[i][1] = b1v.y; h[i][2] = b1v.z; h[i][3] = b1v.w;
    }
#pragma unroll
    for (int bb = 0; bb < 32; bb += 4) {
        float4 wv[4];
#pragma unroll
        for (int u = 0; u < 4; u++) wv[u] = *(const float4*)&w1[(bb + u) * 128 + j0];
#pragma unroll
        for (int i = 0; i < 8; i++) {
            float4 m4 = *(const float4*)&mi[(ng * 8 + i) * 32 + bb];
            h[i][0] = fmaf(m4.x, wv[0].x, h[i][0]);
            h[i][1] = fmaf(m4.x, wv[0].y, h[i][1]);
            h[i][2] = fmaf(m4.x, wv[0].z, h[i][2]);
            h[i][3] = fmaf(m4.x, wv[0].w, h[i][3]);
            h[i][0] = fmaf(m4.y, wv[1].x, h[i][0]);
            h[i][1] = fmaf(m4.y, wv[1].y, h[i][1]);
            h[i][2] = fmaf(m4.y, wv[1].z, h[i][2]);
            h[i][3] = fmaf(m4.y, wv[1].w, h[i][3]);
            h[i][0] = fmaf(m4.z, wv[2].x, h[i][0]);
            h[i][1] = fmaf(m4.z, wv[2].y, h[i][1]);
            h[i][2] = fmaf(m4.z, wv[2].z, h[i][2]);
            h[i][3] = fmaf(m4.z, wv[2].w, h[i][3]);
            h[i][0] = fmaf(m4.w, wv[3].x, h[i][0]);
            h[i][1] = fmaf(m4.w, wv[3].y, h[i][1]);
            h[i][2] = fmaf(m4.w, wv[3].z, h[i][2]);
            h[i][3] = fmaf(m4.w, wv[3].w, h[i][3]);
        }
    }
#pragma unroll
    for (int i = 0; i < 8; i++) {
        float4 sv = make_float4(silu_f(h[i][0]), silu_f(h[i][1]),
                                silu_f(h[i][2]), silu_f(h[i][3]));
        *(float4*)&sh[(ng * 8 + i) * 128 + j0] = sv;
    }
    __syncthreads();

    float4 b2v = *(const float4*)&b2[j0];
    float acc[8][4];
#pragma unroll
    for (int i = 0; i < 8; i++) {
        acc[i][0] = b2v.x; acc[i][1] = b2v.y; acc[i][2] = b2v.z; acc[i][3] = b2v.w;
    }
    for (int hb = 0; hb < 128; hb += 4) {
        float4 wv[4];
#pragma unroll
        for (int u = 0; u < 4; u++) wv[u] = *(const float4*)&w2[(hb + u) * 128 + j0];
#pragma unroll
        for (int i = 0; i < 8; i++) {
            float4 s4 = *(const float4*)&sh[(ng * 8 + i) * 128 + hb];
            acc[i][0] = fmaf(s4.x, wv[0].x, acc[i][0]);
            acc[i][1] = fmaf(s4.x, wv[0].y, acc[i][1]);
            acc[i][2] = fmaf(s4.x, wv[0].z, acc[i][2]);
            acc[i][3] = fmaf(s4.x, wv[0].w, acc[i][3]);
            acc[i][0] = fmaf(s4.y, wv[1].x, acc[i][0]);
            acc[i][1] = fmaf(s4.y, wv[1].y, acc[i][1]);
            acc[i][2] = fmaf(s4.y, wv[1].z, acc[i][2]);
            acc[i][3] = fmaf(s4.y, wv[1].w, acc[i][3]);
            acc[i][0] = fmaf(s4.z, wv[2].x, acc[i][0]);
            acc[i][1] = fmaf(s4.z, wv[2].y, acc[i][1]);
            acc[i][2] = fmaf(s4.z, wv[2].z, acc[i][2]);
            acc[i][3] = fmaf(s4.z, wv[2].w, acc[i][3]);
            acc[i][0] = fmaf(s4.w, wv[3].x, acc[i][0]);
            acc[i][1] = fmaf(s4.w, wv[3].y, acc[i][1]);
            acc[i][2] = fmaf(s4.w, wv[3].z, acc[i][2]);
            acc[i][3] = fmaf(s4.w, wv[3].w, acc[i][3]);
        }
    }
#pragma unroll
    for (int i = 0; i < 8; i++) {
        int n = n0 + ng * 8 + i;
        if (n < N_NODES) {
            *(float4*)&out[(size_t)n * 128 + j0] =
                make_float4(acc[i][0], acc[i][1], acc[i][2], acc[i][3]);
        }
    }
}

extern "C" void kernel_launch(void* const* d_in, const int* in_sizes, int n_in,
                              void* d_out, int out_size, void* d_ws, size_t ws_size,
                              hipStream_t stream) {
    (void)in_sizes; (void)n_in; (void)out_size; (void)ws_size;
    const float* feat    = (const float*)d_in[0];
    const float* dis_vec = (const float*)d_in[1];
    const float* cj_w1   = (const float*)d_in[2];
    const float* cj_b1   = (const float*)d_in[3];
    const float* cj_w2   = (const float*)d_in[4];
    const float* cj_b2   = (const float*)d_in[5];
    const float* msg_w1  = (const float*)d_in[6];
    const float* msg_b1  = (const float*)d_in[7];
    const float* msg_w2  = (const float*)d_in[8];
    const float* msg_b2  = (const float*)d_in[9];
    const float* filt_w1 = (const float*)d_in[10];
    const float* filt_w2 = (const float*)d_in[11];
    const float* filt_b2 = (const float*)d_in[12];
    const int*   src     = (const int*)d_in[13];
    const int*   dst     = (const int*)d_in[14];
    float* out = (float*)d_out;

    // workspace layout (elements), all 16B aligned; cnt+bsum zeroed in one memset
    float* ws     = (float*)d_ws;
    float* cj     = ws;                        // 50048 floats
    int*   cnt    = (int*)(cj + 50048);        // 50048 ints (zeroed)
    int*   bsum   = cnt + 50048;               // 64 ints   (zeroed)
    int*   offs   = bsum + 64;                 // 50048 ints
    int*   cursor = offs + 50048;              // 50048 ints
    float* msg_in = (float*)(cursor + 50048);  // 1600256 floats
    float* sedge  = msg_in + 1600256;          // 3200000 floats (12.8 MB, 16B/edge)

    hipMemsetAsync(cnt, 0, (50048 + 64) * sizeof(int), stream);

    k_cj_count<<<CJ_BLOCKS + CNT_BLOCKS, 256, 0, stream>>>(feat, cj_w1, cj_b1, cj_w2,
                                                           cj_b2, cj, src, cnt);
    k_scan<<<SCAN_BLOCKS, 1024, 0, stream>>>(cnt, offs, cursor, bsum);
    k_edge<<<EDGE_BLOCKS, 256, 0, stream>>>(src, dst, dis_vec, cj, cursor, sedge,
                                            filt_w1, filt_w2, filt_b2,
                                            out + (size_t)N_NODES * NA);
    k_agg<<<(N_NODES + 3) / 4, 256, 0, stream>>>(sedge, offs, cnt, msg_in);
    k_msg<<<(N_NODES + 63) / 64, 256, 0, stream>>>(msg_in, msg_w1, msg_b1, msg_w2, msg_b2, out);
}